// Round 5
// baseline (883.485 us; speedup 1.0000x reference)
//
#include <hip/hip_runtime.h>
#include <hip/hip_bf16.h>

// Round 5: fused kernel, 3 MFMA *recompute* passes — no logit tile in
// registers (R4's acc[64] spilled: 248 VGPR vs 256 needed -> scratch-latency
// bound at 1.6 TB/s).  MFMA is ~3% of wave cycles; recompute is cheaper
// than holding.
//   P1: S = sum exp(logit)      (no max-subtract: logit = 2*cos in [-2,2],
//                                exp in [0.135, 7.39] — overflow-free; diff
//                                vs reference is ~1 ulp, threshold margin
//                                is 1.9e-3)
//   P2: recompute -> hard_shrink -> L1
//   P3: recompute -> scale by 1/L1 -> single weight store + ballot-sparse
//       read accumulation (mem rows L2-resident; all-shrunk rows skip free)
// Per-pass recompute is instruction-identical -> bitwise-consistent
// threshold decisions.

#define NM 4096
#define HD 64
#define NROWS 32768  // 16*2048

typedef short bf16x8 __attribute__((ext_vector_type(8)));
typedef float f32x4  __attribute__((ext_vector_type(4)));

// ---- prep: normalized rows -> bf16 [row][k], scale folded in ----
__global__ __launch_bounds__(256) void prep_rows(const float* __restrict__ src,
                                                 ushort* __restrict__ dst,
                                                 float scale) {
    const int wave = threadIdx.x >> 6, lane = threadIdx.x & 63;
    const long row = (long)blockIdx.x * 4 + wave;
    float v = src[row * HD + lane];
    float s = v * v;
#pragma unroll
    for (int o = 32; o; o >>= 1) s += __shfl_xor(s, o, 64);
    const float inv = scale / fmaxf(sqrtf(s), 1e-12f);
    __hip_bfloat16 h = __float2bfloat16(v * inv);
    dst[row * HD + lane] = *reinterpret_cast<ushort*>(&h);
}

// A-frag: lane holds xb[m0+(lane&15)][q*8..+7], q=lane>>4.  B-frag same on mb.
// C/D: col = lane&15, row = q*4 + reg   [verified layout, learn_hip m89/m91].
__global__ __launch_bounds__(256) void fused_mem3(const ushort* __restrict__ xb,
                                                  const ushort* __restrict__ mb,
                                                  const float* __restrict__ mem,
                                                  float* __restrict__ out_w,
                                                  float* __restrict__ out_read) {
    const int wv = threadIdx.x >> 6, lane = threadIdx.x & 63;
    const int q = lane >> 4, c = lane & 15;
    const int m0 = blockIdx.x * 16;
    const int nbase = wv * 1024;

    __shared__ float sS[4][16];
    __shared__ float sL[4][16];
    __shared__ float sred[4][16][64];  // cross-wave read partials, 16 KB

    const bf16x8 a0 = *(const bf16x8*)(xb + (long)(m0 + c) * HD + q * 8);
    const bf16x8 a1 = *(const bf16x8*)(xb + (long)(m0 + c) * HD + q * 8 + 32);
    const ushort* mstrip = mb + (long)nbase * HD + q * 8;

    // ---- pass 1: sum of exp ----
    float sm[4] = {0.0f, 0.0f, 0.0f, 0.0f};
#pragma unroll 8
    for (int i = 0; i < 64; i++) {
        const ushort* mrow = mstrip + (long)(i * 16 + c) * HD;
        const bf16x8 b0 = *(const bf16x8*)(mrow);
        const bf16x8 b1 = *(const bf16x8*)(mrow + 32);
        f32x4 t = {0.0f, 0.0f, 0.0f, 0.0f};
        t = __builtin_amdgcn_mfma_f32_16x16x32_bf16(a0, b0, t, 0, 0, 0);
        t = __builtin_amdgcn_mfma_f32_16x16x32_bf16(a1, b1, t, 0, 0, 0);
#pragma unroll
        for (int r = 0; r < 4; r++) sm[r] += __expf(t[r]);
    }
#pragma unroll
    for (int o = 1; o < 16; o <<= 1)
#pragma unroll
        for (int r = 0; r < 4; r++) sm[r] += __shfl_xor(sm[r], o, 64);
    if (c == 0)
#pragma unroll
        for (int r = 0; r < 4; r++) sS[wv][q * 4 + r] = sm[r];
    __syncthreads();
    float rS[4];
#pragma unroll
    for (int r = 0; r < 4; r++)
        rS[r] = 1.0f / (sS[0][q * 4 + r] + sS[1][q * 4 + r] +
                        sS[2][q * 4 + r] + sS[3][q * 4 + r]);

    // ---- pass 2: hard_shrink_relu + L1 ----
    float l1[4] = {0.0f, 0.0f, 0.0f, 0.0f};
#pragma unroll 8
    for (int i = 0; i < 64; i++) {
        const ushort* mrow = mstrip + (long)(i * 16 + c) * HD;
        const bf16x8 b0 = *(const bf16x8*)(mrow);
        const bf16x8 b1 = *(const bf16x8*)(mrow + 32);
        f32x4 t = {0.0f, 0.0f, 0.0f, 0.0f};
        t = __builtin_amdgcn_mfma_f32_16x16x32_bf16(a0, b0, t, 0, 0, 0);
        t = __builtin_amdgcn_mfma_f32_16x16x32_bf16(a1, b1, t, 0, 0, 0);
#pragma unroll
        for (int r = 0; r < 4; r++) {
            float w  = __expf(t[r]) * rS[r];
            float d  = w - 0.0025f;
            l1[r] += __fdividef(fmaxf(d, 0.0f) * w, fabsf(d) + 1e-12f);
        }
    }
#pragma unroll
    for (int o = 1; o < 16; o <<= 1)
#pragma unroll
        for (int r = 0; r < 4; r++) l1[r] += __shfl_xor(l1[r], o, 64);
    if (c == 0)
#pragma unroll
        for (int r = 0; r < 4; r++) sL[wv][q * 4 + r] = l1[r];
    __syncthreads();
    float rL[4];
#pragma unroll
    for (int r = 0; r < 4; r++)
        rL[r] = 1.0f / fmaxf(sL[0][q * 4 + r] + sL[1][q * 4 + r] +
                             sL[2][q * 4 + r] + sL[3][q * 4 + r], 1e-12f);

    // ---- pass 3: final weights (single store) + sparse read accum ----
    float racc[16];
#pragma unroll
    for (int r = 0; r < 16; r++) racc[r] = 0.0f;
    float* wbase = out_w + (long)(m0 + q * 4) * NM + c;
#pragma unroll 4
    for (int i = 0; i < 64; i++) {
        const int n0 = nbase + i * 16;
        const ushort* mrow = mstrip + (long)(i * 16 + c) * HD;
        const bf16x8 b0 = *(const bf16x8*)(mrow);
        const bf16x8 b1 = *(const bf16x8*)(mrow + 32);
        f32x4 t = {0.0f, 0.0f, 0.0f, 0.0f};
        t = __builtin_amdgcn_mfma_f32_16x16x32_bf16(a0, b0, t, 0, 0, 0);
        t = __builtin_amdgcn_mfma_f32_16x16x32_bf16(a1, b1, t, 0, 0, 0);
        float wf[4];
#pragma unroll
        for (int r = 0; r < 4; r++) {
            float w  = __expf(t[r]) * rS[r];
            float d  = w - 0.0025f;
            float sh = __fdividef(fmaxf(d, 0.0f) * w, fabsf(d) + 1e-12f);
            wf[r] = sh * rL[r];
            wbase[(long)r * NM + n0] = wf[r];
        }

        const bool nz = (wf[0] != 0.0f) | (wf[1] != 0.0f) |
                        (wf[2] != 0.0f) | (wf[3] != 0.0f);
        unsigned long long mask = __ballot(nz);
        while (mask) {
            const int j = __ffsll((long long)mask) - 1;
            mask &= (mask - 1);
            const int qj = j >> 4, cj = j & 15;
            float b0v = __shfl(wf[0], j, 64), b1v = __shfl(wf[1], j, 64);
            float b2v = __shfl(wf[2], j, 64), b3v = __shfl(wf[3], j, 64);
            const float mv = mem[(long)(n0 + cj) * HD + lane];
            switch (qj) {  // wave-uniform branch
                case 0: racc[0]  += b0v * mv; racc[1]  += b1v * mv;
                        racc[2]  += b2v * mv; racc[3]  += b3v * mv; break;
                case 1: racc[4]  += b0v * mv; racc[5]  += b1v * mv;
                        racc[6]  += b2v * mv; racc[7]  += b3v * mv; break;
                case 2: racc[8]  += b0v * mv; racc[9]  += b1v * mv;
                        racc[10] += b2v * mv; racc[11] += b3v * mv; break;
                default: racc[12] += b0v * mv; racc[13] += b1v * mv;
                         racc[14] += b2v * mv; racc[15] += b3v * mv; break;
            }
        }
    }

    // ---- combine read partials across waves, store ----
#pragma unroll
    for (int r = 0; r < 16; r++) sred[wv][r][lane] = racc[r];
    __syncthreads();
#pragma unroll
    for (int rr = 0; rr < 4; rr++) {
        const int row = wv * 4 + rr;
        const float v = sred[0][row][lane] + sred[1][row][lane] +
                        sred[2][row][lane] + sred[3][row][lane];
        out_read[(long)(m0 + row) * HD + lane] = v;
    }
}

extern "C" void kernel_launch(void* const* d_in, const int* in_sizes, int n_in,
                              void* d_out, int out_size, void* d_ws, size_t ws_size,
                              hipStream_t stream) {
    const float* x   = (const float*)d_in[0];
    const float* mem = (const float*)d_in[1];
    ushort* xb       = (ushort*)d_ws;                 // 32768*64 bf16 = 4 MB
    ushort* mb       = xb + (long)NROWS * HD;         // 4096*64 bf16 = 512 KB
    float* out_read  = (float*)d_out;                 // [32768*64]
    float* out_w     = out_read + (long)NROWS * HD;   // [32768*4096]

    prep_rows<<<NROWS / 4, 256, 0, stream>>>(x, xb, 2.0f);  // 1/T folded
    prep_rows<<<NM / 4, 256, 0, stream>>>(mem, mb, 1.0f);
    fused_mem3<<<NROWS / 16, 256, 0, stream>>>(xb, mb, mem, out_w, out_read);
}

// Round 6
// 705.324 us; speedup vs baseline: 1.2526x; 1.2526x over previous
//
#include <hip/hip_runtime.h>
#include <hip/hip_bf16.h>

// Round 6: R5's 3-pass recompute structure + B staged in *MFMA-fragment
// order* (swizzled at prep).  R3-R5's limiter was the b-fragment gather:
// lane c reading mb rows 128 B apart => 64 cache lines per wave-load
// (~64 TA-cyc each).  Swizzled chunks make every b-load a contiguous
// 1 KB wave-load (8 lines).
//   mbs layout: chunk t (16 n-rows) = [frag0: lane0..63 x 8bf16][frag1: ...]
//               (2 KB per chunk, 512 KB total, L2-resident)
//   P1: S = sum exp(logit)   (logits in [-2,2] -> no max-subtract needed)
//   P2: recompute -> hard_shrink -> L1
//   P3: recompute -> scale -> single weight store + ballot-sparse read accum
// Recompute passes are instruction-identical -> consistent threshold bits.

#define NM 4096
#define HD 64
#define NROWS 32768  // 16*2048

typedef short bf16x8 __attribute__((ext_vector_type(8)));
typedef float f32x4  __attribute__((ext_vector_type(4)));

// ---- prep: normalized x rows -> bf16 [row][k], scale folded in ----
__global__ __launch_bounds__(256) void prep_rows(const float* __restrict__ src,
                                                 ushort* __restrict__ dst,
                                                 float scale) {
    const int wave = threadIdx.x >> 6, lane = threadIdx.x & 63;
    const long row = (long)blockIdx.x * 4 + wave;
    float v = src[row * HD + lane];
    float s = v * v;
#pragma unroll
    for (int o = 32; o; o >>= 1) s += __shfl_xor(s, o, 64);
    const float inv = scale / fmaxf(sqrtf(s), 1e-12f);
    __hip_bfloat16 h = __float2bfloat16(v * inv);
    dst[row * HD + lane] = *reinterpret_cast<ushort*>(&h);
}

// ---- prep: normalized memories -> swizzled MFMA B-fragment order ----
// For row n, k: chunk t=n>>4, c=n&15; frag f=k>>5; lane l=((k>>3)&3)*16+c;
// element j=k&7.  ushort addr = t*1024 + f*512 + l*8 + j.
__global__ __launch_bounds__(256) void prep_m_swz(const float* __restrict__ mem,
                                                  ushort* __restrict__ mbs) {
    const int wave = threadIdx.x >> 6, lane = threadIdx.x & 63;
    const int row = blockIdx.x * 4 + wave;   // n
    float v = mem[row * HD + lane];          // k = lane
    float s = v * v;
#pragma unroll
    for (int o = 32; o; o >>= 1) s += __shfl_xor(s, o, 64);
    const float inv = 1.0f / fmaxf(sqrtf(s), 1e-12f);
    __hip_bfloat16 h = __float2bfloat16(v * inv);
    const int t = row >> 4, c = row & 15;
    const int k = lane;
    const int f = k >> 5, q = (k >> 3) & 3, j = k & 7;
    mbs[(long)t * 1024 + f * 512 + (q * 16 + c) * 8 + j] =
        *reinterpret_cast<ushort*>(&h);
}

// A-frag: lane holds xb[m0+(lane&15)][q*8..+7], q=lane>>4 (one-time gather).
// B-frag: coalesced from swizzled mbs.
// C/D: col = lane&15, row = q*4 + reg   [verified layout, learn_hip m89/m91].
__global__ __launch_bounds__(256) void fused_mem3(const ushort* __restrict__ xb,
                                                  const ushort* __restrict__ mbs,
                                                  const float* __restrict__ mem,
                                                  float* __restrict__ out_w,
                                                  float* __restrict__ out_read) {
    const int wv = threadIdx.x >> 6, lane = threadIdx.x & 63;
    const int q = lane >> 4, c = lane & 15;
    const int m0 = blockIdx.x * 16;
    const int nbase = wv * 1024;

    __shared__ float sS[4][16];
    __shared__ float sL[4][16];
    __shared__ float sred[4][16][64];  // cross-wave read partials, 16 KB

    const bf16x8 a0 = *(const bf16x8*)(xb + (long)(m0 + c) * HD + q * 8);
    const bf16x8 a1 = *(const bf16x8*)(xb + (long)(m0 + c) * HD + q * 8 + 32);
    const ushort* mstrip = mbs + (long)(wv * 64) * 1024;  // this wave's 64 chunks

    // ---- pass 1: sum of exp ----
    float sm[4] = {0.0f, 0.0f, 0.0f, 0.0f};
#pragma unroll 8
    for (int i = 0; i < 64; i++) {
        const ushort* mc = mstrip + (long)i * 1024 + lane * 8;
        const bf16x8 b0 = *(const bf16x8*)(mc);
        const bf16x8 b1 = *(const bf16x8*)(mc + 512);
        f32x4 t = {0.0f, 0.0f, 0.0f, 0.0f};
        t = __builtin_amdgcn_mfma_f32_16x16x32_bf16(a0, b0, t, 0, 0, 0);
        t = __builtin_amdgcn_mfma_f32_16x16x32_bf16(a1, b1, t, 0, 0, 0);
#pragma unroll
        for (int r = 0; r < 4; r++) sm[r] += __expf(t[r]);
    }
#pragma unroll
    for (int o = 1; o < 16; o <<= 1)
#pragma unroll
        for (int r = 0; r < 4; r++) sm[r] += __shfl_xor(sm[r], o, 64);
    if (c == 0)
#pragma unroll
        for (int r = 0; r < 4; r++) sS[wv][q * 4 + r] = sm[r];
    __syncthreads();
    float rS[4];
#pragma unroll
    for (int r = 0; r < 4; r++)
        rS[r] = 1.0f / (sS[0][q * 4 + r] + sS[1][q * 4 + r] +
                        sS[2][q * 4 + r] + sS[3][q * 4 + r]);

    // ---- pass 2: hard_shrink_relu + L1 ----
    float l1[4] = {0.0f, 0.0f, 0.0f, 0.0f};
#pragma unroll 8
    for (int i = 0; i < 64; i++) {
        const ushort* mc = mstrip + (long)i * 1024 + lane * 8;
        const bf16x8 b0 = *(const bf16x8*)(mc);
        const bf16x8 b1 = *(const bf16x8*)(mc + 512);
        f32x4 t = {0.0f, 0.0f, 0.0f, 0.0f};
        t = __builtin_amdgcn_mfma_f32_16x16x32_bf16(a0, b0, t, 0, 0, 0);
        t = __builtin_amdgcn_mfma_f32_16x16x32_bf16(a1, b1, t, 0, 0, 0);
#pragma unroll
        for (int r = 0; r < 4; r++) {
            float w  = __expf(t[r]) * rS[r];
            float d  = w - 0.0025f;
            l1[r] += __fdividef(fmaxf(d, 0.0f) * w, fabsf(d) + 1e-12f);
        }
    }
#pragma unroll
    for (int o = 1; o < 16; o <<= 1)
#pragma unroll
        for (int r = 0; r < 4; r++) l1[r] += __shfl_xor(l1[r], o, 64);
    if (c == 0)
#pragma unroll
        for (int r = 0; r < 4; r++) sL[wv][q * 4 + r] = l1[r];
    __syncthreads();
    float rL[4];
#pragma unroll
    for (int r = 0; r < 4; r++)
        rL[r] = 1.0f / fmaxf(sL[0][q * 4 + r] + sL[1][q * 4 + r] +
                             sL[2][q * 4 + r] + sL[3][q * 4 + r], 1e-12f);

    // ---- pass 3: final weights (single store) + sparse read accum ----
    float racc[16];
#pragma unroll
    for (int r = 0; r < 16; r++) racc[r] = 0.0f;
    float* wbase = out_w + (long)(m0 + q * 4) * NM + c;
#pragma unroll 4
    for (int i = 0; i < 64; i++) {
        const int n0 = nbase + i * 16;
        const ushort* mc = mstrip + (long)i * 1024 + lane * 8;
        const bf16x8 b0 = *(const bf16x8*)(mc);
        const bf16x8 b1 = *(const bf16x8*)(mc + 512);
        f32x4 t = {0.0f, 0.0f, 0.0f, 0.0f};
        t = __builtin_amdgcn_mfma_f32_16x16x32_bf16(a0, b0, t, 0, 0, 0);
        t = __builtin_amdgcn_mfma_f32_16x16x32_bf16(a1, b1, t, 0, 0, 0);
        float wf[4];
#pragma unroll
        for (int r = 0; r < 4; r++) {
            float w  = __expf(t[r]) * rS[r];
            float d  = w - 0.0025f;
            float sh = __fdividef(fmaxf(d, 0.0f) * w, fabsf(d) + 1e-12f);
            wf[r] = sh * rL[r];
            wbase[(long)r * NM + n0] = wf[r];
        }

        const bool nz = (wf[0] != 0.0f) | (wf[1] != 0.0f) |
                        (wf[2] != 0.0f) | (wf[3] != 0.0f);
        unsigned long long mask = __ballot(nz);
        while (mask) {
            const int j = __ffsll((long long)mask) - 1;
            mask &= (mask - 1);
            const int qj = j >> 4, cj = j & 15;
            float b0v = __shfl(wf[0], j, 64), b1v = __shfl(wf[1], j, 64);
            float b2v = __shfl(wf[2], j, 64), b3v = __shfl(wf[3], j, 64);
            const float mv = mem[(long)(n0 + cj) * HD + lane];
            switch (qj) {  // wave-uniform branch
                case 0: racc[0]  += b0v * mv; racc[1]  += b1v * mv;
                        racc[2]  += b2v * mv; racc[3]  += b3v * mv; break;
                case 1: racc[4]  += b0v * mv; racc[5]  += b1v * mv;
                        racc[6]  += b2v * mv; racc[7]  += b3v * mv; break;
                case 2: racc[8]  += b0v * mv; racc[9]  += b1v * mv;
                        racc[10] += b2v * mv; racc[11] += b3v * mv; break;
                default: racc[12] += b0v * mv; racc[13] += b1v * mv;
                         racc[14] += b2v * mv; racc[15] += b3v * mv; break;
            }
        }
    }

    // ---- combine read partials across waves, store ----
#pragma unroll
    for (int r = 0; r < 16; r++) sred[wv][r][lane] = racc[r];
    __syncthreads();
#pragma unroll
    for (int rr = 0; rr < 4; rr++) {
        const int row = wv * 4 + rr;
        const float v = sred[0][row][lane] + sred[1][row][lane] +
                        sred[2][row][lane] + sred[3][row][lane];
        out_read[(long)(m0 + row) * HD + lane] = v;
    }
}

extern "C" void kernel_launch(void* const* d_in, const int* in_sizes, int n_in,
                              void* d_out, int out_size, void* d_ws, size_t ws_size,
                              hipStream_t stream) {
    const float* x   = (const float*)d_in[0];
    const float* mem = (const float*)d_in[1];
    ushort* xb       = (ushort*)d_ws;                 // 32768*64 bf16 = 4 MB
    ushort* mbs      = xb + (long)NROWS * HD;         // swizzled B, 512 KB
    float* out_read  = (float*)d_out;                 // [32768*64]
    float* out_w     = out_read + (long)NROWS * HD;   // [32768*4096]

    prep_rows<<<NROWS / 4, 256, 0, stream>>>(x, xb, 2.0f);  // 1/T folded
    prep_m_swz<<<NM / 4, 256, 0, stream>>>(mem, mbs);
    fused_mem3<<<NROWS / 16, 256, 0, stream>>>(xb, mbs, mem, out_w, out_read);
}

// Round 7
// 683.594 us; speedup vs baseline: 1.2924x; 1.0318x over previous
//
#include <hip/hip_runtime.h>
#include <hip/hip_bf16.h>

// Round 7: R6's 3-pass MFMA-recompute + P3 epilogue transposed through
// per-wave LDS tiles so weight stores are float4 streams (1 KB/instr,
// 4x256B segments) instead of scattered 4B stores (4x64B segments).
// Evidence: all scattered-store variants plateau 1.5-2.2 TB/s; float4
// streaming (R2 finish) hit 5.4 TB/s.
//   mbs: B pre-swizzled to MFMA fragment order (1 KB coalesced wave-loads)
//   P1: S = sum exp(logit)   (logits in [-2,2] -> no max-subtract needed)
//   P2: recompute -> hard_shrink -> L1
//   P3: recompute -> scale -> per-wave LDS transpose -> float4 stores
//       + ballot-sparse read accumulation (free when all weights shrink)
// Tile stride 68 floats: 16B-aligned rows for ds_read_b128, <=2-way bank
// aliasing (free).  Wave-private tile => in-wave lgkmcnt fence, no barrier.

#define NM 4096
#define HD 64
#define NROWS 32768  // 16*2048

typedef short bf16x8 __attribute__((ext_vector_type(8)));
typedef float f32x4  __attribute__((ext_vector_type(4)));

// ---- prep: normalized x rows -> bf16 [row][k], scale folded in ----
__global__ __launch_bounds__(256) void prep_rows(const float* __restrict__ src,
                                                 ushort* __restrict__ dst,
                                                 float scale) {
    const int wave = threadIdx.x >> 6, lane = threadIdx.x & 63;
    const long row = (long)blockIdx.x * 4 + wave;
    float v = src[row * HD + lane];
    float s = v * v;
#pragma unroll
    for (int o = 32; o; o >>= 1) s += __shfl_xor(s, o, 64);
    const float inv = scale / fmaxf(sqrtf(s), 1e-12f);
    __hip_bfloat16 h = __float2bfloat16(v * inv);
    dst[row * HD + lane] = *reinterpret_cast<ushort*>(&h);
}

// ---- prep: normalized memories -> swizzled MFMA B-fragment order ----
__global__ __launch_bounds__(256) void prep_m_swz(const float* __restrict__ mem,
                                                  ushort* __restrict__ mbs) {
    const int wave = threadIdx.x >> 6, lane = threadIdx.x & 63;
    const int row = blockIdx.x * 4 + wave;   // n
    float v = mem[row * HD + lane];          // k = lane
    float s = v * v;
#pragma unroll
    for (int o = 32; o; o >>= 1) s += __shfl_xor(s, o, 64);
    const float inv = 1.0f / fmaxf(sqrtf(s), 1e-12f);
    __hip_bfloat16 h = __float2bfloat16(v * inv);
    const int t = row >> 4, c = row & 15;
    const int k = lane;
    const int f = k >> 5, q = (k >> 3) & 3, j = k & 7;
    mbs[(long)t * 1024 + f * 512 + (q * 16 + c) * 8 + j] =
        *reinterpret_cast<ushort*>(&h);
}

// A-frag: lane holds xb[m0+(lane&15)][q*8..+7], q=lane>>4 (one-time gather).
// B-frag: coalesced from swizzled mbs.
// C/D: col = lane&15, row = q*4 + reg   [verified layout, learn_hip m89/m91].
__global__ __launch_bounds__(256) void fused_mem3(const ushort* __restrict__ xb,
                                                  const ushort* __restrict__ mbs,
                                                  const float* __restrict__ mem,
                                                  float* __restrict__ out_w,
                                                  float* __restrict__ out_read) {
    const int wv = threadIdx.x >> 6, lane = threadIdx.x & 63;
    const int q = lane >> 4, c = lane & 15;
    const int m0 = blockIdx.x * 16;
    const int nbase = wv * 1024;

    __shared__ float sS[4][16];
    __shared__ float sL[4][16];
    __shared__ float sred[4][16][64];   // cross-wave read partials, 16 KB
    __shared__ float tile[4][16][68];   // per-wave transpose tiles, 17.4 KB

    const bf16x8 a0 = *(const bf16x8*)(xb + (long)(m0 + c) * HD + q * 8);
    const bf16x8 a1 = *(const bf16x8*)(xb + (long)(m0 + c) * HD + q * 8 + 32);
    const ushort* mstrip = mbs + (long)(wv * 64) * 1024;  // this wave's chunks

    // ---- pass 1: sum of exp ----
    float sm[4] = {0.0f, 0.0f, 0.0f, 0.0f};
#pragma unroll 8
    for (int i = 0; i < 64; i++) {
        const ushort* mc = mstrip + (long)i * 1024 + lane * 8;
        const bf16x8 b0 = *(const bf16x8*)(mc);
        const bf16x8 b1 = *(const bf16x8*)(mc + 512);
        f32x4 t = {0.0f, 0.0f, 0.0f, 0.0f};
        t = __builtin_amdgcn_mfma_f32_16x16x32_bf16(a0, b0, t, 0, 0, 0);
        t = __builtin_amdgcn_mfma_f32_16x16x32_bf16(a1, b1, t, 0, 0, 0);
#pragma unroll
        for (int r = 0; r < 4; r++) sm[r] += __expf(t[r]);
    }
#pragma unroll
    for (int o = 1; o < 16; o <<= 1)
#pragma unroll
        for (int r = 0; r < 4; r++) sm[r] += __shfl_xor(sm[r], o, 64);
    if (c == 0)
#pragma unroll
        for (int r = 0; r < 4; r++) sS[wv][q * 4 + r] = sm[r];
    __syncthreads();
    float rS[4];
#pragma unroll
    for (int r = 0; r < 4; r++)
        rS[r] = 1.0f / (sS[0][q * 4 + r] + sS[1][q * 4 + r] +
                        sS[2][q * 4 + r] + sS[3][q * 4 + r]);

    // ---- pass 2: hard_shrink_relu + L1 ----
    float l1[4] = {0.0f, 0.0f, 0.0f, 0.0f};
#pragma unroll 8
    for (int i = 0; i < 64; i++) {
        const ushort* mc = mstrip + (long)i * 1024 + lane * 8;
        const bf16x8 b0 = *(const bf16x8*)(mc);
        const bf16x8 b1 = *(const bf16x8*)(mc + 512);
        f32x4 t = {0.0f, 0.0f, 0.0f, 0.0f};
        t = __builtin_amdgcn_mfma_f32_16x16x32_bf16(a0, b0, t, 0, 0, 0);
        t = __builtin_amdgcn_mfma_f32_16x16x32_bf16(a1, b1, t, 0, 0, 0);
#pragma unroll
        for (int r = 0; r < 4; r++) {
            float w  = __expf(t[r]) * rS[r];
            float d  = w - 0.0025f;
            l1[r] += __fdividef(fmaxf(d, 0.0f) * w, fabsf(d) + 1e-12f);
        }
    }
#pragma unroll
    for (int o = 1; o < 16; o <<= 1)
#pragma unroll
        for (int r = 0; r < 4; r++) l1[r] += __shfl_xor(l1[r], o, 64);
    if (c == 0)
#pragma unroll
        for (int r = 0; r < 4; r++) sL[wv][q * 4 + r] = l1[r];
    __syncthreads();
    float rL[4];
#pragma unroll
    for (int r = 0; r < 4; r++)
        rL[r] = 1.0f / fmaxf(sL[0][q * 4 + r] + sL[1][q * 4 + r] +
                             sL[2][q * 4 + r] + sL[3][q * 4 + r], 1e-12f);

    // ---- pass 3: recompute -> LDS transpose -> float4 stores + read accum ----
    float racc[16];
#pragma unroll
    for (int r = 0; r < 16; r++) racc[r] = 0.0f;
    const int row_t = lane >> 4;  // store-phase row within quad-group
    const int c4    = lane & 15;  // store-phase float4 index

    for (int g = 0; g < 16; g++) {
#pragma unroll
        for (int ii = 0; ii < 4; ii++) {
            const int i  = g * 4 + ii;
            const int n0 = nbase + i * 16;
            const ushort* mc = mstrip + (long)i * 1024 + lane * 8;
            const bf16x8 b0 = *(const bf16x8*)(mc);
            const bf16x8 b1 = *(const bf16x8*)(mc + 512);
            f32x4 t = {0.0f, 0.0f, 0.0f, 0.0f};
            t = __builtin_amdgcn_mfma_f32_16x16x32_bf16(a0, b0, t, 0, 0, 0);
            t = __builtin_amdgcn_mfma_f32_16x16x32_bf16(a1, b1, t, 0, 0, 0);
            float wf[4];
#pragma unroll
            for (int r = 0; r < 4; r++) {
                float w  = __expf(t[r]) * rS[r];
                float d  = w - 0.0025f;
                float sh = __fdividef(fmaxf(d, 0.0f) * w, fabsf(d) + 1e-12f);
                wf[r] = sh * rL[r];
                tile[wv][q * 4 + r][ii * 16 + c] = wf[r];
            }

            const bool nz = (wf[0] != 0.0f) | (wf[1] != 0.0f) |
                            (wf[2] != 0.0f) | (wf[3] != 0.0f);
            unsigned long long mask = __ballot(nz);
            while (mask) {
                const int j = __ffsll((long long)mask) - 1;
                mask &= (mask - 1);
                const int qj = j >> 4, cj = j & 15;
                float b0v = __shfl(wf[0], j, 64), b1v = __shfl(wf[1], j, 64);
                float b2v = __shfl(wf[2], j, 64), b3v = __shfl(wf[3], j, 64);
                const float mv = mem[(long)(n0 + cj) * HD + lane];
                switch (qj) {  // wave-uniform branch
                    case 0: racc[0]  += b0v * mv; racc[1]  += b1v * mv;
                            racc[2]  += b2v * mv; racc[3]  += b3v * mv; break;
                    case 1: racc[4]  += b0v * mv; racc[5]  += b1v * mv;
                            racc[6]  += b2v * mv; racc[7]  += b3v * mv; break;
                    case 2: racc[8]  += b0v * mv; racc[9]  += b1v * mv;
                            racc[10] += b2v * mv; racc[11] += b3v * mv; break;
                    default: racc[12] += b0v * mv; racc[13] += b1v * mv;
                             racc[14] += b2v * mv; racc[15] += b3v * mv; break;
                }
            }
        }

        // in-wave fence: tile writes -> tile reads (wave-private region)
        __asm__ volatile("s_waitcnt lgkmcnt(0)" ::: "memory");

        const int gbase = nbase + g * 64;
#pragma unroll
        for (int s = 0; s < 4; s++) {
            const int row = s * 4 + row_t;
            float4 v = *(const float4*)&tile[wv][row][c4 * 4];
            *(float4*)(out_w + (long)(m0 + row) * NM + gbase + c4 * 4) = v;
        }
        // DS ops are in-order per wave: next group's writes can't pass reads.
    }

    // ---- combine read partials across waves, store ----
#pragma unroll
    for (int r = 0; r < 16; r++) sred[wv][r][lane] = racc[r];
    __syncthreads();
#pragma unroll
    for (int rr = 0; rr < 4; rr++) {
        const int row = wv * 4 + rr;
        const float v = sred[0][row][lane] + sred[1][row][lane] +
                        sred[2][row][lane] + sred[3][row][lane];
        out_read[(long)(m0 + row) * HD + lane] = v;
    }
}

extern "C" void kernel_launch(void* const* d_in, const int* in_sizes, int n_in,
                              void* d_out, int out_size, void* d_ws, size_t ws_size,
                              hipStream_t stream) {
    const float* x   = (const float*)d_in[0];
    const float* mem = (const float*)d_in[1];
    ushort* xb       = (ushort*)d_ws;                 // 32768*64 bf16 = 4 MB
    ushort* mbs      = xb + (long)NROWS * HD;         // swizzled B, 512 KB
    float* out_read  = (float*)d_out;                 // [32768*64]
    float* out_w     = out_read + (long)NROWS * HD;   // [32768*4096]

    prep_rows<<<NROWS / 4, 256, 0, stream>>>(x, xb, 2.0f);  // 1/T folded
    prep_m_swz<<<NM / 4, 256, 0, stream>>>(mem, mbs);
    fused_mem3<<<NROWS / 16, 256, 0, stream>>>(xb, mbs, mem, out_w, out_read);
}

// Round 8
// 618.752 us; speedup vs baseline: 1.4278x; 1.1048x over previous
//
#include <hip/hip_runtime.h>
#include <hip/hip_bf16.h>

// Round 8: threshold-gated lazy evaluation.
// After P1 (sum of exp), a weight survives hard-shrink iff
//   exp(t)*rS > lambda  <=>  t > tau = ln(lambda*S).
// P1 banks tmax[i] = max logit over the lane's 4 rows (64 VGPRs).  P2/P3
// then gate on a register compare + ballot: clean iters need NO load, NO
// MFMA, NO exp.  Clean P3 groups stream float4 zeros; dirty ones take the
// exact LDS-transpose path (R7).  tau gets a -1e-3 logit-space margin so
// all borderline values go through the exact relu(d)*w/(|d|+eps) formula.
//   mbs: B pre-swizzled to MFMA fragment order (1 KB coalesced wave-loads)
// Common case here (max softmax weight ~6e-4 << lambda=2.5e-3): every
// weight shrinks -> kernel = P1 + ballots + zero-store stream.

#define NM 4096
#define HD 64
#define NROWS 32768  // 16*2048

typedef short bf16x8 __attribute__((ext_vector_type(8)));
typedef float f32x4  __attribute__((ext_vector_type(4)));

// ---- prep: normalized x rows -> bf16 [row][k], scale folded in ----
__global__ __launch_bounds__(256) void prep_rows(const float* __restrict__ src,
                                                 ushort* __restrict__ dst,
                                                 float scale) {
    const int wave = threadIdx.x >> 6, lane = threadIdx.x & 63;
    const long row = (long)blockIdx.x * 4 + wave;
    float v = src[row * HD + lane];
    float s = v * v;
#pragma unroll
    for (int o = 32; o; o >>= 1) s += __shfl_xor(s, o, 64);
    const float inv = scale / fmaxf(sqrtf(s), 1e-12f);
    __hip_bfloat16 h = __float2bfloat16(v * inv);
    dst[row * HD + lane] = *reinterpret_cast<ushort*>(&h);
}

// ---- prep: normalized memories -> swizzled MFMA B-fragment order ----
__global__ __launch_bounds__(256) void prep_m_swz(const float* __restrict__ mem,
                                                  ushort* __restrict__ mbs) {
    const int wave = threadIdx.x >> 6, lane = threadIdx.x & 63;
    const int row = blockIdx.x * 4 + wave;   // n
    float v = mem[row * HD + lane];          // k = lane
    float s = v * v;
#pragma unroll
    for (int o = 32; o; o >>= 1) s += __shfl_xor(s, o, 64);
    const float inv = 1.0f / fmaxf(sqrtf(s), 1e-12f);
    __hip_bfloat16 h = __float2bfloat16(v * inv);
    const int t = row >> 4, c = row & 15;
    const int k = lane;
    const int f = k >> 5, q = (k >> 3) & 3, j = k & 7;
    mbs[(long)t * 1024 + f * 512 + (q * 16 + c) * 8 + j] =
        *reinterpret_cast<ushort*>(&h);
}

// A-frag: lane holds xb[m0+(lane&15)][q*8..+7], q=lane>>4 (one-time gather).
// B-frag: coalesced from swizzled mbs.
// C/D: col = lane&15, row = q*4 + reg   [verified layout, learn_hip m89/m91].
__global__ __launch_bounds__(256, 2) void fused_gate(const ushort* __restrict__ xb,
                                                     const ushort* __restrict__ mbs,
                                                     const float* __restrict__ mem,
                                                     float* __restrict__ out_w,
                                                     float* __restrict__ out_read) {
    const int wv = threadIdx.x >> 6, lane = threadIdx.x & 63;
    const int q = lane >> 4, c = lane & 15;
    const int m0 = blockIdx.x * 16;
    const int nbase = wv * 1024;

    __shared__ float sS[4][16];
    __shared__ float sL[4][16];
    __shared__ float sred[4][16][64];   // cross-wave read partials, 16 KB
    __shared__ float tile[4][16][68];   // per-wave transpose tiles, 17.4 KB

    const bf16x8 a0 = *(const bf16x8*)(xb + (long)(m0 + c) * HD + q * 8);
    const bf16x8 a1 = *(const bf16x8*)(xb + (long)(m0 + c) * HD + q * 8 + 32);
    const ushort* mstrip = mbs + (long)(wv * 64) * 1024;  // this wave's chunks

    // ---- pass 1: sum of exp; bank per-iter max logit ----
    float tmax[64];
    float sm[4] = {0.0f, 0.0f, 0.0f, 0.0f};
#pragma unroll 4
    for (int i = 0; i < 64; i++) {
        const ushort* mc = mstrip + (long)i * 1024 + lane * 8;
        const bf16x8 b0 = *(const bf16x8*)(mc);
        const bf16x8 b1 = *(const bf16x8*)(mc + 512);
        f32x4 t = {0.0f, 0.0f, 0.0f, 0.0f};
        t = __builtin_amdgcn_mfma_f32_16x16x32_bf16(a0, b0, t, 0, 0, 0);
        t = __builtin_amdgcn_mfma_f32_16x16x32_bf16(a1, b1, t, 0, 0, 0);
        tmax[i] = fmaxf(fmaxf(t[0], t[1]), fmaxf(t[2], t[3]));
#pragma unroll
        for (int r = 0; r < 4; r++) sm[r] += __expf(t[r]);
    }
#pragma unroll
    for (int o = 1; o < 16; o <<= 1)
#pragma unroll
        for (int r = 0; r < 4; r++) sm[r] += __shfl_xor(sm[r], o, 64);
    if (c == 0)
#pragma unroll
        for (int r = 0; r < 4; r++) sS[wv][q * 4 + r] = sm[r];
    __syncthreads();
    float rS[4], tmin = 1e30f;
#pragma unroll
    for (int r = 0; r < 4; r++) {
        const float S = sS[0][q * 4 + r] + sS[1][q * 4 + r] +
                        sS[2][q * 4 + r] + sS[3][q * 4 + r];
        rS[r] = 1.0f / S;
        // survival threshold in logit space, conservative by 1e-3
        const float tau = __logf(0.0025f * S) - 1e-3f;
        tmin = fminf(tmin, tau);
    }

    // ---- pass 2: L1 of shrunk weights — gated ----
    float l1[4] = {0.0f, 0.0f, 0.0f, 0.0f};
    for (int i = 0; i < 64; i++) {
        if (__ballot(tmax[i] > tmin)) {  // wave-uniform; rare
            const ushort* mc = mstrip + (long)i * 1024 + lane * 8;
            const bf16x8 b0 = *(const bf16x8*)(mc);
            const bf16x8 b1 = *(const bf16x8*)(mc + 512);
            f32x4 t = {0.0f, 0.0f, 0.0f, 0.0f};
            t = __builtin_amdgcn_mfma_f32_16x16x32_bf16(a0, b0, t, 0, 0, 0);
            t = __builtin_amdgcn_mfma_f32_16x16x32_bf16(a1, b1, t, 0, 0, 0);
#pragma unroll
            for (int r = 0; r < 4; r++) {
                float w  = __expf(t[r]) * rS[r];
                float d  = w - 0.0025f;
                l1[r] += __fdividef(fmaxf(d, 0.0f) * w, fabsf(d) + 1e-12f);
            }
        }
    }
#pragma unroll
    for (int o = 1; o < 16; o <<= 1)
#pragma unroll
        for (int r = 0; r < 4; r++) l1[r] += __shfl_xor(l1[r], o, 64);
    if (c == 0)
#pragma unroll
        for (int r = 0; r < 4; r++) sL[wv][q * 4 + r] = l1[r];
    __syncthreads();
    float rL[4];
#pragma unroll
    for (int r = 0; r < 4; r++)
        rL[r] = 1.0f / fmaxf(sL[0][q * 4 + r] + sL[1][q * 4 + r] +
                             sL[2][q * 4 + r] + sL[3][q * 4 + r], 1e-12f);

    // ---- pass 3: gated stores + sparse read accum ----
    float racc[16];
#pragma unroll
    for (int r = 0; r < 16; r++) racc[r] = 0.0f;
    const int row_t = lane >> 4;  // store-phase row within quad-group
    const int c4    = lane & 15;  // store-phase float4 index
    const float4 z4 = make_float4(0.0f, 0.0f, 0.0f, 0.0f);

    for (int g = 0; g < 16; g++) {
        unsigned long long dirty = 0;
#pragma unroll
        for (int ii = 0; ii < 4; ii++)
            dirty |= __ballot(tmax[g * 4 + ii] > tmin);
        const int gbase = nbase + g * 64;

        if (!dirty) {
            // whole 16x64 subtile shrinks to zero: stream zeros
#pragma unroll
            for (int s = 0; s < 4; s++) {
                const int row = s * 4 + row_t;
                *(float4*)(out_w + (long)(m0 + row) * NM + gbase + c4 * 4) = z4;
            }
            continue;
        }

        // exact path (rare): recompute, shrink, LDS transpose, read accum
#pragma unroll
        for (int ii = 0; ii < 4; ii++) {
            const int i  = g * 4 + ii;
            const int n0 = nbase + i * 16;
            const ushort* mc = mstrip + (long)i * 1024 + lane * 8;
            const bf16x8 b0 = *(const bf16x8*)(mc);
            const bf16x8 b1 = *(const bf16x8*)(mc + 512);
            f32x4 t = {0.0f, 0.0f, 0.0f, 0.0f};
            t = __builtin_amdgcn_mfma_f32_16x16x32_bf16(a0, b0, t, 0, 0, 0);
            t = __builtin_amdgcn_mfma_f32_16x16x32_bf16(a1, b1, t, 0, 0, 0);
            float wf[4];
#pragma unroll
            for (int r = 0; r < 4; r++) {
                float w  = __expf(t[r]) * rS[r];
                float d  = w - 0.0025f;
                float sh = __fdividef(fmaxf(d, 0.0f) * w, fabsf(d) + 1e-12f);
                wf[r] = sh * rL[r];
                tile[wv][q * 4 + r][ii * 16 + c] = wf[r];
            }

            const bool nz = (wf[0] != 0.0f) | (wf[1] != 0.0f) |
                            (wf[2] != 0.0f) | (wf[3] != 0.0f);
            unsigned long long mask = __ballot(nz);
            while (mask) {
                const int j = __ffsll((long long)mask) - 1;
                mask &= (mask - 1);
                const int qj = j >> 4, cj = j & 15;
                float b0v = __shfl(wf[0], j, 64), b1v = __shfl(wf[1], j, 64);
                float b2v = __shfl(wf[2], j, 64), b3v = __shfl(wf[3], j, 64);
                const float mv = mem[(long)(n0 + cj) * HD + lane];
                switch (qj) {  // wave-uniform branch
                    case 0: racc[0]  += b0v * mv; racc[1]  += b1v * mv;
                            racc[2]  += b2v * mv; racc[3]  += b3v * mv; break;
                    case 1: racc[4]  += b0v * mv; racc[5]  += b1v * mv;
                            racc[6]  += b2v * mv; racc[7]  += b3v * mv; break;
                    case 2: racc[8]  += b0v * mv; racc[9]  += b1v * mv;
                            racc[10] += b2v * mv; racc[11] += b3v * mv; break;
                    default: racc[12] += b0v * mv; racc[13] += b1v * mv;
                             racc[14] += b2v * mv; racc[15] += b3v * mv; break;
                }
            }
        }

        // in-wave fence: tile writes -> tile reads (wave-private region)
        __asm__ volatile("s_waitcnt lgkmcnt(0)" ::: "memory");
#pragma unroll
        for (int s = 0; s < 4; s++) {
            const int row = s * 4 + row_t;
            float4 v = *(const float4*)&tile[wv][row][c4 * 4];
            *(float4*)(out_w + (long)(m0 + row) * NM + gbase + c4 * 4) = v;
        }
    }

    // ---- combine read partials across waves, store ----
#pragma unroll
    for (int r = 0; r < 16; r++) sred[wv][r][lane] = racc[r];
    __syncthreads();
#pragma unroll
    for (int rr = 0; rr < 4; rr++) {
        const int row = wv * 4 + rr;
        const float v = sred[0][row][lane] + sred[1][row][lane] +
                        sred[2][row][lane] + sred[3][row][lane];
        out_read[(long)(m0 + row) * HD + lane] = v;
    }
}

extern "C" void kernel_launch(void* const* d_in, const int* in_sizes, int n_in,
                              void* d_out, int out_size, void* d_ws, size_t ws_size,
                              hipStream_t stream) {
    const float* x   = (const float*)d_in[0];
    const float* mem = (const float*)d_in[1];
    ushort* xb       = (ushort*)d_ws;                 // 32768*64 bf16 = 4 MB
    ushort* mbs      = xb + (long)NROWS * HD;         // swizzled B, 512 KB
    float* out_read  = (float*)d_out;                 // [32768*64]
    float* out_w     = out_read + (long)NROWS * HD;   // [32768*4096]

    prep_rows<<<NROWS / 4, 256, 0, stream>>>(x, xb, 2.0f);  // 1/T folded
    prep_m_swz<<<NM / 4, 256, 0, stream>>>(mem, mbs);
    fused_gate<<<NROWS / 16, 256, 0, stream>>>(xb, mbs, mem, out_w, out_read);
}

// Round 9
// 601.466 us; speedup vs baseline: 1.4689x; 1.0287x over previous
//
#include <hip/hip_runtime.h>
#include <hip/hip_bf16.h>

// Round 9: producer/consumer split for attribution + linear stores.
//   k_stats: P1 (sum-exp via MFMA, pair-banked tmax), gated L1, per-row
//            {rS,rL} + per-(block,wave) 16-bit group-dirty masks -> ws,
//            sparse read accumulation -> out_read.  No weight stores.
//   k_write: all-clean block (common case: every weight shrinks) -> pure
//            linear float4 zero-memset of its contiguous 256 KB region
//            (fillBuffer shape, 6.3 TB/s).  Dirty blocks recompute weights
//            exactly (bit-identical MFMA + same rS/rL bits) via LDS
//            transpose.
// Gate: weight survives shrink iff logit t > tau = ln(lambda*S); tau gets
// -1e-3 margin so borderline values take the exact formula.

#define NM 4096
#define HD 64
#define NROWS 32768  // 16*2048

typedef short bf16x8 __attribute__((ext_vector_type(8)));
typedef float f32x4  __attribute__((ext_vector_type(4)));

// ---- prep: normalized x rows -> bf16 [row][k], scale folded in ----
__global__ __launch_bounds__(256) void prep_rows(const float* __restrict__ src,
                                                 ushort* __restrict__ dst,
                                                 float scale) {
    const int wave = threadIdx.x >> 6, lane = threadIdx.x & 63;
    const long row = (long)blockIdx.x * 4 + wave;
    float v = src[row * HD + lane];
    float s = v * v;
#pragma unroll
    for (int o = 32; o; o >>= 1) s += __shfl_xor(s, o, 64);
    const float inv = scale / fmaxf(sqrtf(s), 1e-12f);
    __hip_bfloat16 h = __float2bfloat16(v * inv);
    dst[row * HD + lane] = *reinterpret_cast<ushort*>(&h);
}

// ---- prep: normalized memories -> swizzled MFMA B-fragment order ----
__global__ __launch_bounds__(256) void prep_m_swz(const float* __restrict__ mem,
                                                  ushort* __restrict__ mbs) {
    const int wave = threadIdx.x >> 6, lane = threadIdx.x & 63;
    const int row = blockIdx.x * 4 + wave;   // n
    float v = mem[row * HD + lane];          // k = lane
    float s = v * v;
#pragma unroll
    for (int o = 32; o; o >>= 1) s += __shfl_xor(s, o, 64);
    const float inv = 1.0f / fmaxf(sqrtf(s), 1e-12f);
    __hip_bfloat16 h = __float2bfloat16(v * inv);
    const int t = row >> 4, c = row & 15;
    const int k = lane;
    const int f = k >> 5, q = (k >> 3) & 3, j = k & 7;
    mbs[(long)t * 1024 + f * 512 + (q * 16 + c) * 8 + j] =
        *reinterpret_cast<ushort*>(&h);
}

// A-frag: lane holds xb[m0+(lane&15)][q*8..+7], q=lane>>4.
// C/D: col = lane&15, row = q*4 + reg   [verified layout, learn_hip m89/m91].
__global__ __launch_bounds__(256, 3) void k_stats(const ushort* __restrict__ xb,
                                                  const ushort* __restrict__ mbs,
                                                  const float* __restrict__ mem,
                                                  float2* __restrict__ stats,
                                                  uint* __restrict__ masks,
                                                  float* __restrict__ out_read) {
    const int wv = threadIdx.x >> 6, lane = threadIdx.x & 63;
    const int q = lane >> 4, c = lane & 15;
    const int m0 = blockIdx.x * 16;
    const int nbase = wv * 1024;

    __shared__ float sS[4][16];
    __shared__ float sL[4][16];
    __shared__ float sred[4][16][64];   // cross-wave read partials, 16 KB

    const bf16x8 a0 = *(const bf16x8*)(xb + (long)(m0 + c) * HD + q * 8);
    const bf16x8 a1 = *(const bf16x8*)(xb + (long)(m0 + c) * HD + q * 8 + 32);
    const ushort* mstrip = mbs + (long)(wv * 64) * 1024;  // this wave's chunks

    // ---- P1: sum of exp; bank per-PAIR max logit (32 VGPRs) ----
    float tmax2[32];
    float sm[4] = {0.0f, 0.0f, 0.0f, 0.0f};
#pragma unroll 2
    for (int p = 0; p < 32; p++) {
        float tm;
        {
            const ushort* mc = mstrip + (long)(2 * p) * 1024 + lane * 8;
            const bf16x8 b0 = *(const bf16x8*)(mc);
            const bf16x8 b1 = *(const bf16x8*)(mc + 512);
            f32x4 t = {0.0f, 0.0f, 0.0f, 0.0f};
            t = __builtin_amdgcn_mfma_f32_16x16x32_bf16(a0, b0, t, 0, 0, 0);
            t = __builtin_amdgcn_mfma_f32_16x16x32_bf16(a1, b1, t, 0, 0, 0);
            tm = fmaxf(fmaxf(t[0], t[1]), fmaxf(t[2], t[3]));
#pragma unroll
            for (int r = 0; r < 4; r++) sm[r] += __expf(t[r]);
        }
        {
            const ushort* mc = mstrip + (long)(2 * p + 1) * 1024 + lane * 8;
            const bf16x8 b0 = *(const bf16x8*)(mc);
            const bf16x8 b1 = *(const bf16x8*)(mc + 512);
            f32x4 t = {0.0f, 0.0f, 0.0f, 0.0f};
            t = __builtin_amdgcn_mfma_f32_16x16x32_bf16(a0, b0, t, 0, 0, 0);
            t = __builtin_amdgcn_mfma_f32_16x16x32_bf16(a1, b1, t, 0, 0, 0);
            tm = fmaxf(tm, fmaxf(fmaxf(t[0], t[1]), fmaxf(t[2], t[3])));
#pragma unroll
            for (int r = 0; r < 4; r++) sm[r] += __expf(t[r]);
        }
        tmax2[p] = tm;
    }
#pragma unroll
    for (int o = 1; o < 16; o <<= 1)
#pragma unroll
        for (int r = 0; r < 4; r++) sm[r] += __shfl_xor(sm[r], o, 64);
    if (c == 0)
#pragma unroll
        for (int r = 0; r < 4; r++) sS[wv][q * 4 + r] = sm[r];
    __syncthreads();
    float rS[4], tmin = 1e30f;
#pragma unroll
    for (int r = 0; r < 4; r++) {
        const float S = sS[0][q * 4 + r] + sS[1][q * 4 + r] +
                        sS[2][q * 4 + r] + sS[3][q * 4 + r];
        rS[r] = 1.0f / S;
        const float tau = __logf(0.0025f * S) - 1e-3f;  // conservative
        tmin = fminf(tmin, tau);
    }

    // ---- P2: gated L1 ----
    float l1[4] = {0.0f, 0.0f, 0.0f, 0.0f};
    for (int p = 0; p < 32; p++) {
        if (__ballot(tmax2[p] > tmin)) {  // wave-uniform; rare
#pragma unroll
            for (int h = 0; h < 2; h++) {
                const ushort* mc = mstrip + (long)(2 * p + h) * 1024 + lane * 8;
                const bf16x8 b0 = *(const bf16x8*)(mc);
                const bf16x8 b1 = *(const bf16x8*)(mc + 512);
                f32x4 t = {0.0f, 0.0f, 0.0f, 0.0f};
                t = __builtin_amdgcn_mfma_f32_16x16x32_bf16(a0, b0, t, 0, 0, 0);
                t = __builtin_amdgcn_mfma_f32_16x16x32_bf16(a1, b1, t, 0, 0, 0);
#pragma unroll
                for (int r = 0; r < 4; r++) {
                    float w = __expf(t[r]) * rS[r];
                    float d = w - 0.0025f;
                    l1[r] += __fdividef(fmaxf(d, 0.0f) * w, fabsf(d) + 1e-12f);
                }
            }
        }
    }
#pragma unroll
    for (int o = 1; o < 16; o <<= 1)
#pragma unroll
        for (int r = 0; r < 4; r++) l1[r] += __shfl_xor(l1[r], o, 64);
    if (c == 0)
#pragma unroll
        for (int r = 0; r < 4; r++) sL[wv][q * 4 + r] = l1[r];
    __syncthreads();
    float rL[4];
#pragma unroll
    for (int r = 0; r < 4; r++)
        rL[r] = 1.0f / fmaxf(sL[0][q * 4 + r] + sL[1][q * 4 + r] +
                             sL[2][q * 4 + r] + sL[3][q * 4 + r], 1e-12f);
    if (wv == 0 && c == 0)
#pragma unroll
        for (int r = 0; r < 4; r++)
            stats[m0 + q * 4 + r] = make_float2(rS[r], rL[r]);

    // ---- P3': dirty recompute -> read accum + group masks (no w stores) ----
    float racc[16];
#pragma unroll
    for (int r = 0; r < 16; r++) racc[r] = 0.0f;
    uint gm = 0;
    for (int g = 0; g < 16; g++) {
        unsigned long long d0 = __ballot(tmax2[2 * g] > tmin);
        unsigned long long d1 = __ballot(tmax2[2 * g + 1] > tmin);
        if (!(d0 | d1)) continue;
        gm |= 1u << g;
#pragma unroll
        for (int ii = 0; ii < 4; ii++) {
            const int i  = g * 4 + ii;
            const int n0 = nbase + i * 16;
            const ushort* mc = mstrip + (long)i * 1024 + lane * 8;
            const bf16x8 b0 = *(const bf16x8*)(mc);
            const bf16x8 b1 = *(const bf16x8*)(mc + 512);
            f32x4 t = {0.0f, 0.0f, 0.0f, 0.0f};
            t = __builtin_amdgcn_mfma_f32_16x16x32_bf16(a0, b0, t, 0, 0, 0);
            t = __builtin_amdgcn_mfma_f32_16x16x32_bf16(a1, b1, t, 0, 0, 0);
            float wf[4];
#pragma unroll
            for (int r = 0; r < 4; r++) {
                float w  = __expf(t[r]) * rS[r];
                float d  = w - 0.0025f;
                float sh = __fdividef(fmaxf(d, 0.0f) * w, fabsf(d) + 1e-12f);
                wf[r] = sh * rL[r];
            }
            const bool nz = (wf[0] != 0.0f) | (wf[1] != 0.0f) |
                            (wf[2] != 0.0f) | (wf[3] != 0.0f);
            unsigned long long mask = __ballot(nz);
            while (mask) {
                const int j = __ffsll((long long)mask) - 1;
                mask &= (mask - 1);
                const int qj = j >> 4, cj = j & 15;
                float b0v = __shfl(wf[0], j, 64), b1v = __shfl(wf[1], j, 64);
                float b2v = __shfl(wf[2], j, 64), b3v = __shfl(wf[3], j, 64);
                const float mv = mem[(long)(n0 + cj) * HD + lane];
                switch (qj) {  // wave-uniform branch
                    case 0: racc[0]  += b0v * mv; racc[1]  += b1v * mv;
                            racc[2]  += b2v * mv; racc[3]  += b3v * mv; break;
                    case 1: racc[4]  += b0v * mv; racc[5]  += b1v * mv;
                            racc[6]  += b2v * mv; racc[7]  += b3v * mv; break;
                    case 2: racc[8]  += b0v * mv; racc[9]  += b1v * mv;
                            racc[10] += b2v * mv; racc[11] += b3v * mv; break;
                    default: racc[12] += b0v * mv; racc[13] += b1v * mv;
                             racc[14] += b2v * mv; racc[15] += b3v * mv; break;
                }
            }
        }
    }
    if (lane == 0) masks[blockIdx.x * 4 + wv] = gm;

    // ---- combine read partials across waves, store out_read ----
#pragma unroll
    for (int r = 0; r < 16; r++) sred[wv][r][lane] = racc[r];
    __syncthreads();
#pragma unroll
    for (int rr = 0; rr < 4; rr++) {
        const int row = wv * 4 + rr;
        const float v = sred[0][row][lane] + sred[1][row][lane] +
                        sred[2][row][lane] + sred[3][row][lane];
        out_read[(long)(m0 + row) * HD + lane] = v;
    }
}

// ---- K_write: clean block -> linear 256 KB zero-memset; dirty -> exact ----
__global__ __launch_bounds__(256) void k_write(const ushort* __restrict__ xb,
                                               const ushort* __restrict__ mbs,
                                               const float2* __restrict__ stats,
                                               const uint* __restrict__ masks,
                                               float* __restrict__ out_w) {
    const int tid = threadIdx.x;
    const int wv = tid >> 6, lane = tid & 63;
    const int q = lane >> 4, c = lane & 15;
    const int m0 = blockIdx.x * 16;

    __shared__ uint sgm[4];
    __shared__ float tile[4][16][68];

    if (tid < 4) sgm[tid] = masks[blockIdx.x * 4 + tid];
    __syncthreads();
    const uint any = sgm[0] | sgm[1] | sgm[2] | sgm[3];
    const float4 z4 = make_float4(0.0f, 0.0f, 0.0f, 0.0f);

    if (!any) {
        // whole 16x4096 tile shrinks to zero: contiguous linear memset
        float4* base = (float4*)(out_w + (long)m0 * NM);
#pragma unroll
        for (int it = 0; it < 64; it++) base[(long)it * 256 + tid] = z4;
        return;
    }

    // dirty block (rare): per-wave strip, recompute exact (bit-identical)
    const int nbase = wv * 1024;
    const uint gm = sgm[wv];
    const bf16x8 a0 = *(const bf16x8*)(xb + (long)(m0 + c) * HD + q * 8);
    const bf16x8 a1 = *(const bf16x8*)(xb + (long)(m0 + c) * HD + q * 8 + 32);
    const ushort* mstrip = mbs + (long)(wv * 64) * 1024;
    float rS[4], rL[4];
#pragma unroll
    for (int r = 0; r < 4; r++) {
        float2 s = stats[m0 + q * 4 + r];
        rS[r] = s.x; rL[r] = s.y;
    }
    const int row_t = lane >> 4, c4 = lane & 15;

    for (int g = 0; g < 16; g++) {
        const int gbase = nbase + g * 64;
        if (!((gm >> g) & 1u)) {
#pragma unroll
            for (int s = 0; s < 4; s++) {
                const int row = s * 4 + row_t;
                *(float4*)(out_w + (long)(m0 + row) * NM + gbase + c4 * 4) = z4;
            }
            continue;
        }
#pragma unroll
        for (int ii = 0; ii < 4; ii++) {
            const int i = g * 4 + ii;
            const ushort* mc = mstrip + (long)i * 1024 + lane * 8;
            const bf16x8 b0 = *(const bf16x8*)(mc);
            const bf16x8 b1 = *(const bf16x8*)(mc + 512);
            f32x4 t = {0.0f, 0.0f, 0.0f, 0.0f};
            t = __builtin_amdgcn_mfma_f32_16x16x32_bf16(a0, b0, t, 0, 0, 0);
            t = __builtin_amdgcn_mfma_f32_16x16x32_bf16(a1, b1, t, 0, 0, 0);
#pragma unroll
            for (int r = 0; r < 4; r++) {
                float w  = __expf(t[r]) * rS[r];
                float d  = w - 0.0025f;
                float sh = __fdividef(fmaxf(d, 0.0f) * w, fabsf(d) + 1e-12f);
                tile[wv][q * 4 + r][ii * 16 + c] = sh * rL[r];
            }
        }
        __asm__ volatile("s_waitcnt lgkmcnt(0)" ::: "memory");
#pragma unroll
        for (int s = 0; s < 4; s++) {
            const int row = s * 4 + row_t;
            float4 v = *(const float4*)&tile[wv][row][c4 * 4];
            *(float4*)(out_w + (long)(m0 + row) * NM + gbase + c4 * 4) = v;
        }
    }
}

extern "C" void kernel_launch(void* const* d_in, const int* in_sizes, int n_in,
                              void* d_out, int out_size, void* d_ws, size_t ws_size,
                              hipStream_t stream) {
    const float* x   = (const float*)d_in[0];
    const float* mem = (const float*)d_in[1];
    ushort* xb       = (ushort*)d_ws;                 // 4 MB
    ushort* mbs      = xb + (long)NROWS * HD;         // 512 KB (swizzled B)
    float2* stats    = (float2*)(mbs + (long)NM * HD);// 256 KB {rS,rL}/row
    uint*   masks    = (uint*)(stats + NROWS);        // 32 KB group-dirty
    float* out_read  = (float*)d_out;                 // [32768*64]
    float* out_w     = out_read + (long)NROWS * HD;   // [32768*4096]

    prep_rows<<<NROWS / 4, 256, 0, stream>>>(x, xb, 2.0f);  // 1/T folded
    prep_m_swz<<<NM / 4, 256, 0, stream>>>(mem, mbs);
    k_stats<<<NROWS / 16, 256, 0, stream>>>(xb, mbs, mem, stats, masks, out_read);
    k_write<<<NROWS / 16, 256, 0, stream>>>(xb, mbs, stats, masks, out_w);
}

// Round 10
// 551.135 us; speedup vs baseline: 1.6030x; 1.0913x over previous
//
#include <hip/hip_runtime.h>
#include <hip/hip_bf16.h>

// Round 10: single fused kernel, overlap-first.
// Split (R9) showed compute-then-store serialization: k_stats+k_write =
// T_c + T_s.  Fused at 4 blocks/CU approaches max(T_c, T_s): block A's
// linear store stream runs under block B's P1 compute.
//   P1: sum-exp via MFMA over the wave's 64 swizzled B-chunks; coarse
//       gate bank tmax8[8] (max logit per 8-chunk group).
//   gate: weight survives shrink iff logit t > tau = ln(lambda*S) (-1e-3
//       margin routes borderline through the exact formula).
//   clean block (common case): linear float4 zero-memset of its contiguous
//       256 KB weight region + zero out_read rows.  No L1, no P2/P3.
//   dirty block (rare): gated L1, exact recompute of all chunks (formula
//       yields exact 0 for shrunk entries), scattered stores, ballot-sparse
//       read accumulation, cross-wave combine.

#define NM 4096
#define HD 64
#define NROWS 32768  // 16*2048

typedef short bf16x8 __attribute__((ext_vector_type(8)));
typedef float f32x4  __attribute__((ext_vector_type(4)));

// ---- prep: normalized x rows -> bf16 [row][k], scale folded in ----
__global__ __launch_bounds__(256) void prep_rows(const float* __restrict__ src,
                                                 ushort* __restrict__ dst,
                                                 float scale) {
    const int wave = threadIdx.x >> 6, lane = threadIdx.x & 63;
    const long row = (long)blockIdx.x * 4 + wave;
    float v = src[row * HD + lane];
    float s = v * v;
#pragma unroll
    for (int o = 32; o; o >>= 1) s += __shfl_xor(s, o, 64);
    const float inv = scale / fmaxf(sqrtf(s), 1e-12f);
    __hip_bfloat16 h = __float2bfloat16(v * inv);
    dst[row * HD + lane] = *reinterpret_cast<ushort*>(&h);
}

// ---- prep: normalized memories -> swizzled MFMA B-fragment order ----
__global__ __launch_bounds__(256) void prep_m_swz(const float* __restrict__ mem,
                                                  ushort* __restrict__ mbs) {
    const int wave = threadIdx.x >> 6, lane = threadIdx.x & 63;
    const int row = blockIdx.x * 4 + wave;   // n
    float v = mem[row * HD + lane];          // k = lane
    float s = v * v;
#pragma unroll
    for (int o = 32; o; o >>= 1) s += __shfl_xor(s, o, 64);
    const float inv = 1.0f / fmaxf(sqrtf(s), 1e-12f);
    __hip_bfloat16 h = __float2bfloat16(v * inv);
    const int t = row >> 4, c = row & 15;
    const int k = lane;
    const int f = k >> 5, q = (k >> 3) & 3, j = k & 7;
    mbs[(long)t * 1024 + f * 512 + (q * 16 + c) * 8 + j] =
        *reinterpret_cast<ushort*>(&h);
}

// A-frag: lane holds xb[m0+(lane&15)][q*8..+7], q=lane>>4.
// C/D: col = lane&15, row = q*4 + reg   [verified layout, learn_hip m89/m91].
__global__ __launch_bounds__(256, 4) void k_fused(const ushort* __restrict__ xb,
                                                  const ushort* __restrict__ mbs,
                                                  const float* __restrict__ mem,
                                                  float* __restrict__ out_w,
                                                  float* __restrict__ out_read) {
    const int tid = threadIdx.x;
    const int wv = tid >> 6, lane = tid & 63;
    const int q = lane >> 4, c = lane & 15;
    const int m0 = blockIdx.x * 16;
    const int nbase = wv * 1024;

    __shared__ float sS[4][16];
    __shared__ float sL[4][16];
    __shared__ uint  sD[4];
    __shared__ float sred[4][16][64];   // cross-wave read partials, 16 KB

    const bf16x8 a0 = *(const bf16x8*)(xb + (long)(m0 + c) * HD + q * 8);
    const bf16x8 a1 = *(const bf16x8*)(xb + (long)(m0 + c) * HD + q * 8 + 32);
    const ushort* mstrip = mbs + (long)(wv * 64) * 1024;  // this wave's chunks

    // ---- P1: sum of exp; bank max logit per 8-chunk group ----
    float tmax8[8];
    float sm[4] = {0.0f, 0.0f, 0.0f, 0.0f};
    for (int g = 0; g < 8; g++) {
        float tm = -1e30f;
#pragma unroll 4
        for (int ii = 0; ii < 8; ii++) {
            const int i = g * 8 + ii;
            const ushort* mc = mstrip + (long)i * 1024 + lane * 8;
            const bf16x8 b0 = *(const bf16x8*)(mc);
            const bf16x8 b1 = *(const bf16x8*)(mc + 512);
            f32x4 t = {0.0f, 0.0f, 0.0f, 0.0f};
            t = __builtin_amdgcn_mfma_f32_16x16x32_bf16(a0, b0, t, 0, 0, 0);
            t = __builtin_amdgcn_mfma_f32_16x16x32_bf16(a1, b1, t, 0, 0, 0);
            tm = fmaxf(tm, fmaxf(fmaxf(t[0], t[1]), fmaxf(t[2], t[3])));
#pragma unroll
            for (int r = 0; r < 4; r++) sm[r] += __expf(t[r]);
        }
        tmax8[g] = tm;
    }
#pragma unroll
    for (int o = 1; o < 16; o <<= 1)
#pragma unroll
        for (int r = 0; r < 4; r++) sm[r] += __shfl_xor(sm[r], o, 64);
    if (c == 0)
#pragma unroll
        for (int r = 0; r < 4; r++) sS[wv][q * 4 + r] = sm[r];
    __syncthreads();
    float rS[4], tmin = 1e30f;
#pragma unroll
    for (int r = 0; r < 4; r++) {
        const float S = sS[0][q * 4 + r] + sS[1][q * 4 + r] +
                        sS[2][q * 4 + r] + sS[3][q * 4 + r];
        rS[r] = 1.0f / S;
        const float tau = __logf(0.0025f * S) - 1e-3f;  // conservative
        tmin = fminf(tmin, tau);
    }

    // ---- block-uniform clean test ----
    uint dmask = 0;
#pragma unroll
    for (int g = 0; g < 8; g++)
        if (__ballot(tmax8[g] > tmin)) dmask |= 1u << g;
    if (lane == 0) sD[wv] = dmask;
    __syncthreads();
    const uint anyd = sD[0] | sD[1] | sD[2] | sD[3];
    const float4 z4 = make_float4(0.0f, 0.0f, 0.0f, 0.0f);

    if (!anyd) {
        // common case: all 16x4096 weights shrink to zero.
        // Linear float4 memset of this block's contiguous 256 KB region.
        float4* base = (float4*)(out_w + (long)m0 * NM);
#pragma unroll 8
        for (int it = 0; it < 64; it++) base[(long)it * 256 + tid] = z4;
        ((float4*)(out_read + (long)m0 * HD))[tid] = z4;
        return;
    }

    // ================= dirty block (rare): exact path =================
    // gated L1 over 8-chunk groups
    float l1[4] = {0.0f, 0.0f, 0.0f, 0.0f};
    for (int g = 0; g < 8; g++) {
        if (!((dmask >> g) & 1u)) continue;   // wave-uniform
        for (int ii = 0; ii < 8; ii++) {
            const int i = g * 8 + ii;
            const ushort* mc = mstrip + (long)i * 1024 + lane * 8;
            const bf16x8 b0 = *(const bf16x8*)(mc);
            const bf16x8 b1 = *(const bf16x8*)(mc + 512);
            f32x4 t = {0.0f, 0.0f, 0.0f, 0.0f};
            t = __builtin_amdgcn_mfma_f32_16x16x32_bf16(a0, b0, t, 0, 0, 0);
            t = __builtin_amdgcn_mfma_f32_16x16x32_bf16(a1, b1, t, 0, 0, 0);
#pragma unroll
            for (int r = 0; r < 4; r++) {
                float w = __expf(t[r]) * rS[r];
                float d = w - 0.0025f;
                l1[r] += __fdividef(fmaxf(d, 0.0f) * w, fabsf(d) + 1e-12f);
            }
        }
    }
#pragma unroll
    for (int o = 1; o < 16; o <<= 1)
#pragma unroll
        for (int r = 0; r < 4; r++) l1[r] += __shfl_xor(l1[r], o, 64);
    if (c == 0)
#pragma unroll
        for (int r = 0; r < 4; r++) sL[wv][q * 4 + r] = l1[r];
    __syncthreads();
    float rL[4];
#pragma unroll
    for (int r = 0; r < 4; r++)
        rL[r] = 1.0f / fmaxf(sL[0][q * 4 + r] + sL[1][q * 4 + r] +
                             sL[2][q * 4 + r] + sL[3][q * 4 + r], 1e-12f);

    // full exact recompute + store + sparse read accum
    float racc[16];
#pragma unroll
    for (int r = 0; r < 16; r++) racc[r] = 0.0f;
    float* wbase = out_w + (long)(m0 + q * 4) * NM + c;
    for (int i = 0; i < 64; i++) {
        const int n0 = nbase + i * 16;
        const ushort* mc = mstrip + (long)i * 1024 + lane * 8;
        const bf16x8 b0 = *(const bf16x8*)(mc);
        const bf16x8 b1 = *(const bf16x8*)(mc + 512);
        f32x4 t = {0.0f, 0.0f, 0.0f, 0.0f};
        t = __builtin_amdgcn_mfma_f32_16x16x32_bf16(a0, b0, t, 0, 0, 0);
        t = __builtin_amdgcn_mfma_f32_16x16x32_bf16(a1, b1, t, 0, 0, 0);
        float wf[4];
#pragma unroll
        for (int r = 0; r < 4; r++) {
            float w  = __expf(t[r]) * rS[r];
            float d  = w - 0.0025f;
            float sh = __fdividef(fmaxf(d, 0.0f) * w, fabsf(d) + 1e-12f);
            wf[r] = sh * rL[r];
            wbase[(long)r * NM + n0] = wf[r];
        }
        const bool nz = (wf[0] != 0.0f) | (wf[1] != 0.0f) |
                        (wf[2] != 0.0f) | (wf[3] != 0.0f);
        unsigned long long mask = __ballot(nz);
        while (mask) {
            const int j = __ffsll((long long)mask) - 1;
            mask &= (mask - 1);
            const int qj = j >> 4, cj = j & 15;
            float b0v = __shfl(wf[0], j, 64), b1v = __shfl(wf[1], j, 64);
            float b2v = __shfl(wf[2], j, 64), b3v = __shfl(wf[3], j, 64);
            const float mv = mem[(long)(n0 + cj) * HD + lane];
            switch (qj) {  // wave-uniform branch
                case 0: racc[0]  += b0v * mv; racc[1]  += b1v * mv;
                        racc[2]  += b2v * mv; racc[3]  += b3v * mv; break;
                case 1: racc[4]  += b0v * mv; racc[5]  += b1v * mv;
                        racc[6]  += b2v * mv; racc[7]  += b3v * mv; break;
                case 2: racc[8]  += b0v * mv; racc[9]  += b1v * mv;
                        racc[10] += b2v * mv; racc[11] += b3v * mv; break;
                default: racc[12] += b0v * mv; racc[13] += b1v * mv;
                         racc[14] += b2v * mv; racc[15] += b3v * mv; break;
            }
        }
    }

    // combine read partials across waves, store out_read
#pragma unroll
    for (int r = 0; r < 16; r++) sred[wv][r][lane] = racc[r];
    __syncthreads();
#pragma unroll
    for (int rr = 0; rr < 4; rr++) {
        const int row = wv * 4 + rr;
        const float v = sred[0][row][lane] + sred[1][row][lane] +
                        sred[2][row][lane] + sred[3][row][lane];
        out_read[(long)(m0 + row) * HD + lane] = v;
    }
}

extern "C" void kernel_launch(void* const* d_in, const int* in_sizes, int n_in,
                              void* d_out, int out_size, void* d_ws, size_t ws_size,
                              hipStream_t stream) {
    const float* x   = (const float*)d_in[0];
    const float* mem = (const float*)d_in[1];
    ushort* xb       = (ushort*)d_ws;                 // 4 MB
    ushort* mbs      = xb + (long)NROWS * HD;         // 512 KB (swizzled B)
    float* out_read  = (float*)d_out;                 // [32768*64]
    float* out_w     = out_read + (long)NROWS * HD;   // [32768*4096]

    prep_rows<<<NROWS / 4, 256, 0, stream>>>(x, xb, 2.0f);  // 1/T folded
    prep_m_swz<<<NM / 4, 256, 0, stream>>>(mem, mbs);
    k_fused<<<NROWS / 16, 256, 0, stream>>>(xb, mbs, mem, out_w, out_read);
}

// Round 11
// 542.469 us; speedup vs baseline: 1.6286x; 1.0160x over previous
//
#include <hip/hip_runtime.h>
#include <hip/hip_bf16.h>

// Round 11: interleaved store/compute.  R10 was bulk-synchronous: all
// co-resident blocks compute P1 (HBM idle) then memset (VALU idle) ->
// T_c + T_s.  Now each P1 iteration issues one fire-and-forget float4
// zero-store into the block's 256 KB weight region; the store stream
// drains under the MFMA/exp compute -> max(T_c, T_s) ~ write floor.
//   - sS/sD cross-wave reductions use raw `s_waitcnt lgkmcnt(0); s_barrier`
//     (LDS-only visibility).  __syncthreads() would emit vmcnt(0) and
//     drain the interleaved stores mid-kernel.
//   - clean block (common: every weight shrinks, max w ~6e-4 << 2.5e-3):
//     zeros already stored; write out_read zeros, exit.
//   - dirty block (rare): real __syncthreads() (vmcnt drain -> zeros
//     committed), gated L1, exact full recompute overwrites the region,
//     ballot-sparse read accumulation.
// Gate: weight survives shrink iff logit t > tau = ln(lambda*S) - 1e-3
// margin (borderline -> exact formula path).

#define NM 4096
#define HD 64
#define NROWS 32768  // 16*2048

typedef short bf16x8 __attribute__((ext_vector_type(8)));
typedef float f32x4  __attribute__((ext_vector_type(4)));

// ---- prep: normalized x rows -> bf16 [row][k], scale folded in ----
__global__ __launch_bounds__(256) void prep_rows(const float* __restrict__ src,
                                                 ushort* __restrict__ dst,
                                                 float scale) {
    const int wave = threadIdx.x >> 6, lane = threadIdx.x & 63;
    const long row = (long)blockIdx.x * 4 + wave;
    float v = src[row * HD + lane];
    float s = v * v;
#pragma unroll
    for (int o = 32; o; o >>= 1) s += __shfl_xor(s, o, 64);
    const float inv = scale / fmaxf(sqrtf(s), 1e-12f);
    __hip_bfloat16 h = __float2bfloat16(v * inv);
    dst[row * HD + lane] = *reinterpret_cast<ushort*>(&h);
}

// ---- prep: normalized memories -> swizzled MFMA B-fragment order ----
__global__ __launch_bounds__(256) void prep_m_swz(const float* __restrict__ mem,
                                                  ushort* __restrict__ mbs) {
    const int wave = threadIdx.x >> 6, lane = threadIdx.x & 63;
    const int row = blockIdx.x * 4 + wave;   // n
    float v = mem[row * HD + lane];          // k = lane
    float s = v * v;
#pragma unroll
    for (int o = 32; o; o >>= 1) s += __shfl_xor(s, o, 64);
    const float inv = 1.0f / fmaxf(sqrtf(s), 1e-12f);
    __hip_bfloat16 h = __float2bfloat16(v * inv);
    const int t = row >> 4, c = row & 15;
    const int k = lane;
    const int f = k >> 5, q = (k >> 3) & 3, j = k & 7;
    mbs[(long)t * 1024 + f * 512 + (q * 16 + c) * 8 + j] =
        *reinterpret_cast<ushort*>(&h);
}

// A-frag: lane holds xb[m0+(lane&15)][q*8..+7], q=lane>>4.
// C/D: col = lane&15, row = q*4 + reg   [verified layout, learn_hip m89/m91].
__global__ __launch_bounds__(256, 4) void k_fused(const ushort* __restrict__ xb,
                                                  const ushort* __restrict__ mbs,
                                                  const float* __restrict__ mem,
                                                  float* __restrict__ out_w,
                                                  float* __restrict__ out_read) {
    const int tid = threadIdx.x;
    const int wv = tid >> 6, lane = tid & 63;
    const int q = lane >> 4, c = lane & 15;
    const int m0 = blockIdx.x * 16;
    const int nbase = wv * 1024;

    __shared__ float sS[4][16];
    __shared__ float sL[4][16];
    __shared__ uint  sD[4];
    __shared__ float sred[4][16][64];   // cross-wave read partials, 16 KB

    const bf16x8 a0 = *(const bf16x8*)(xb + (long)(m0 + c) * HD + q * 8);
    const bf16x8 a1 = *(const bf16x8*)(xb + (long)(m0 + c) * HD + q * 8 + 32);
    const ushort* mstrip = mbs + (long)(wv * 64) * 1024;  // this wave's chunks
    const float4 z4 = make_float4(0.0f, 0.0f, 0.0f, 0.0f);
    float4* zbase = (float4*)(out_w + (long)m0 * NM);     // block's 256 KB

    // ---- P1: sum-exp + gate bank, one zero-store per iteration ----
    float tmax8[8];
    float sm[4] = {0.0f, 0.0f, 0.0f, 0.0f};
    for (int g = 0; g < 8; g++) {
        float tm = -1e30f;
#pragma unroll 4
        for (int ii = 0; ii < 8; ii++) {
            const int i = g * 8 + ii;
            const ushort* mc = mstrip + (long)i * 1024 + lane * 8;
            const bf16x8 b0 = *(const bf16x8*)(mc);
            const bf16x8 b1 = *(const bf16x8*)(mc + 512);
            zbase[(long)i * 256 + tid] = z4;   // fire-and-forget zero-store
            f32x4 t = {0.0f, 0.0f, 0.0f, 0.0f};
            t = __builtin_amdgcn_mfma_f32_16x16x32_bf16(a0, b0, t, 0, 0, 0);
            t = __builtin_amdgcn_mfma_f32_16x16x32_bf16(a1, b1, t, 0, 0, 0);
            tm = fmaxf(tm, fmaxf(fmaxf(t[0], t[1]), fmaxf(t[2], t[3])));
#pragma unroll
            for (int r = 0; r < 4; r++) sm[r] += __expf(t[r]);
        }
        tmax8[g] = tm;
    }
#pragma unroll
    for (int o = 1; o < 16; o <<= 1)
#pragma unroll
        for (int r = 0; r < 4; r++) sm[r] += __shfl_xor(sm[r], o, 64);
    if (c == 0)
#pragma unroll
        for (int r = 0; r < 4; r++) sS[wv][q * 4 + r] = sm[r];
    // LDS-only barrier: do NOT drain the interleaved global stores
    __asm__ volatile("s_waitcnt lgkmcnt(0)\n\ts_barrier" ::: "memory");
    float rS[4], tmin = 1e30f;
#pragma unroll
    for (int r = 0; r < 4; r++) {
        const float S = sS[0][q * 4 + r] + sS[1][q * 4 + r] +
                        sS[2][q * 4 + r] + sS[3][q * 4 + r];
        rS[r] = 1.0f / S;
        const float tau = __logf(0.0025f * S) - 1e-3f;  // conservative
        tmin = fminf(tmin, tau);
    }

    // ---- block-uniform clean test (LDS-only barrier again) ----
    uint dmask = 0;
#pragma unroll
    for (int g = 0; g < 8; g++)
        if (__ballot(tmax8[g] > tmin)) dmask |= 1u << g;
    if (lane == 0) sD[wv] = dmask;
    __asm__ volatile("s_waitcnt lgkmcnt(0)\n\ts_barrier" ::: "memory");
    const uint anyd = sD[0] | sD[1] | sD[2] | sD[3];

    if (!anyd) {
        // common case: zeros already streamed to out_w during P1
        ((float4*)(out_read + (long)m0 * HD))[tid] = z4;
        return;
    }

    // ================= dirty block (rare): exact path =================
    __syncthreads();  // drains vmcnt(0): zero-stores committed before rewrite

    // gated L1 over 8-chunk groups
    float l1[4] = {0.0f, 0.0f, 0.0f, 0.0f};
    for (int g = 0; g < 8; g++) {
        if (!((dmask >> g) & 1u)) continue;   // wave-uniform
        for (int ii = 0; ii < 8; ii++) {
            const int i = g * 8 + ii;
            const ushort* mc = mstrip + (long)i * 1024 + lane * 8;
            const bf16x8 b0 = *(const bf16x8*)(mc);
            const bf16x8 b1 = *(const bf16x8*)(mc + 512);
            f32x4 t = {0.0f, 0.0f, 0.0f, 0.0f};
            t = __builtin_amdgcn_mfma_f32_16x16x32_bf16(a0, b0, t, 0, 0, 0);
            t = __builtin_amdgcn_mfma_f32_16x16x32_bf16(a1, b1, t, 0, 0, 0);
#pragma unroll
            for (int r = 0; r < 4; r++) {
                float w = __expf(t[r]) * rS[r];
                float d = w - 0.0025f;
                l1[r] += __fdividef(fmaxf(d, 0.0f) * w, fabsf(d) + 1e-12f);
            }
        }
    }
#pragma unroll
    for (int o = 1; o < 16; o <<= 1)
#pragma unroll
        for (int r = 0; r < 4; r++) l1[r] += __shfl_xor(l1[r], o, 64);
    if (c == 0)
#pragma unroll
        for (int r = 0; r < 4; r++) sL[wv][q * 4 + r] = l1[r];
    __syncthreads();
    float rL[4];
#pragma unroll
    for (int r = 0; r < 4; r++)
        rL[r] = 1.0f / fmaxf(sL[0][q * 4 + r] + sL[1][q * 4 + r] +
                             sL[2][q * 4 + r] + sL[3][q * 4 + r], 1e-12f);

    // full exact recompute + store + sparse read accum
    float racc[16];
#pragma unroll
    for (int r = 0; r < 16; r++) racc[r] = 0.0f;
    float* wbase = out_w + (long)(m0 + q * 4) * NM + c;
    for (int i = 0; i < 64; i++) {
        const int n0 = nbase + i * 16;
        const ushort* mc = mstrip + (long)i * 1024 + lane * 8;
        const bf16x8 b0 = *(const bf16x8*)(mc);
        const bf16x8 b1 = *(const bf16x8*)(mc + 512);
        f32x4 t = {0.0f, 0.0f, 0.0f, 0.0f};
        t = __builtin_amdgcn_mfma_f32_16x16x32_bf16(a0, b0, t, 0, 0, 0);
        t = __builtin_amdgcn_mfma_f32_16x16x32_bf16(a1, b1, t, 0, 0, 0);
        float wf[4];
#pragma unroll
        for (int r = 0; r < 4; r++) {
            float w  = __expf(t[r]) * rS[r];
            float d  = w - 0.0025f;
            float sh = __fdividef(fmaxf(d, 0.0f) * w, fabsf(d) + 1e-12f);
            wf[r] = sh * rL[r];
            wbase[(long)r * NM + n0] = wf[r];
        }
        const bool nz = (wf[0] != 0.0f) | (wf[1] != 0.0f) |
                        (wf[2] != 0.0f) | (wf[3] != 0.0f);
        unsigned long long mask = __ballot(nz);
        while (mask) {
            const int j = __ffsll((long long)mask) - 1;
            mask &= (mask - 1);
            const int qj = j >> 4, cj = j & 15;
            float b0v = __shfl(wf[0], j, 64), b1v = __shfl(wf[1], j, 64);
            float b2v = __shfl(wf[2], j, 64), b3v = __shfl(wf[3], j, 64);
            const float mv = mem[(long)(n0 + cj) * HD + lane];
            switch (qj) {  // wave-uniform branch
                case 0: racc[0]  += b0v * mv; racc[1]  += b1v * mv;
                        racc[2]  += b2v * mv; racc[3]  += b3v * mv; break;
                case 1: racc[4]  += b0v * mv; racc[5]  += b1v * mv;
                        racc[6]  += b2v * mv; racc[7]  += b3v * mv; break;
                case 2: racc[8]  += b0v * mv; racc[9]  += b1v * mv;
                        racc[10] += b2v * mv; racc[11] += b3v * mv; break;
                default: racc[12] += b0v * mv; racc[13] += b1v * mv;
                         racc[14] += b2v * mv; racc[15] += b3v * mv; break;
            }
        }
    }

    // combine read partials across waves, store out_read
#pragma unroll
    for (int r = 0; r < 16; r++) sred[wv][r][lane] = racc[r];
    __syncthreads();
#pragma unroll
    for (int rr = 0; rr < 4; rr++) {
        const int row = wv * 4 + rr;
        const float v = sred[0][row][lane] + sred[1][row][lane] +
                        sred[2][row][lane] + sred[3][row][lane];
        out_read[(long)(m0 + row) * HD + lane] = v;
    }
}

extern "C" void kernel_launch(void* const* d_in, const int* in_sizes, int n_in,
                              void* d_out, int out_size, void* d_ws, size_t ws_size,
                              hipStream_t stream) {
    const float* x   = (const float*)d_in[0];
    const float* mem = (const float*)d_in[1];
    ushort* xb       = (ushort*)d_ws;                 // 4 MB
    ushort* mbs      = xb + (long)NROWS * HD;         // 512 KB (swizzled B)
    float* out_read  = (float*)d_out;                 // [32768*64]
    float* out_w     = out_read + (long)NROWS * HD;   // [32768*4096]

    prep_rows<<<NROWS / 4, 256, 0, stream>>>(x, xb, 2.0f);  // 1/T folded
    prep_m_swz<<<NM / 4, 256, 0, stream>>>(mem, mbs);
    k_fused<<<NROWS / 16, 256, 0, stream>>>(xb, mbs, mem, out_w, out_read);
}

// Round 12
// 538.793 us; speedup vs baseline: 1.6397x; 1.0068x over previous
//
#include <hip/hip_runtime.h>
#include <hip/hip_bf16.h>

// Round 12: producer/consumer wave specialization.
// R11's same-wave store/compute interleave failed because vmcnt retires in
// issue order: a wave's load-waits also wait for its earlier HBM-paced
// stores.  Fix: 512-thread blocks; waves 0-3 compute P1 (loads only in
// their vmem stream), waves 4-7 stream the block's 256 KB zero weights +
// out_read zeros.  Cross-wave MFMA/VMEM co-scheduling is free (m114).
// __syncthreads() B1 joins at max(T_P1, T_store); its implicit vmcnt(0)
// is exactly the storer drain needed before any dirty overwrite.
//   clean block (common: max softmax w ~6e-4 << lambda=2.5e-3): after B2
//     everyone exits -- storers already wrote everything.
//   dirty block (rare): +2 matched barriers; computers do gated L1, exact
//     recompute (overwrites drained zeros), ballot-sparse read accum.
// Gate: weight survives shrink iff logit t > tau = ln(lambda*S) - 1e-3
// margin (borderline -> exact formula path).

#define NM 4096
#define HD 64
#define NROWS 32768  // 16*2048

typedef short bf16x8 __attribute__((ext_vector_type(8)));
typedef float f32x4  __attribute__((ext_vector_type(4)));

// ---- prep: normalized x rows -> bf16 [row][k], scale folded in ----
__global__ __launch_bounds__(256) void prep_rows(const float* __restrict__ src,
                                                 ushort* __restrict__ dst,
                                                 float scale) {
    const int wave = threadIdx.x >> 6, lane = threadIdx.x & 63;
    const long row = (long)blockIdx.x * 4 + wave;
    float v = src[row * HD + lane];
    float s = v * v;
#pragma unroll
    for (int o = 32; o; o >>= 1) s += __shfl_xor(s, o, 64);
    const float inv = scale / fmaxf(sqrtf(s), 1e-12f);
    __hip_bfloat16 h = __float2bfloat16(v * inv);
    dst[row * HD + lane] = *reinterpret_cast<ushort*>(&h);
}

// ---- prep: normalized memories -> swizzled MFMA B-fragment order ----
__global__ __launch_bounds__(256) void prep_m_swz(const float* __restrict__ mem,
                                                  ushort* __restrict__ mbs) {
    const int wave = threadIdx.x >> 6, lane = threadIdx.x & 63;
    const int row = blockIdx.x * 4 + wave;   // n
    float v = mem[row * HD + lane];          // k = lane
    float s = v * v;
#pragma unroll
    for (int o = 32; o; o >>= 1) s += __shfl_xor(s, o, 64);
    const float inv = 1.0f / fmaxf(sqrtf(s), 1e-12f);
    __hip_bfloat16 h = __float2bfloat16(v * inv);
    const int t = row >> 4, c = row & 15;
    const int k = lane;
    const int f = k >> 5, q = (k >> 3) & 3, j = k & 7;
    mbs[(long)t * 1024 + f * 512 + (q * 16 + c) * 8 + j] =
        *reinterpret_cast<ushort*>(&h);
}

// A-frag: lane holds xb[m0+(lane&15)][q*8..+7], q=lane>>4.
// C/D: col = lane&15, row = q*4 + reg   [verified layout, learn_hip m89/m91].
__global__ __launch_bounds__(512, 4) void k_ps(const ushort* __restrict__ xb,
                                               const ushort* __restrict__ mbs,
                                               const float* __restrict__ mem,
                                               float* __restrict__ out_w,
                                               float* __restrict__ out_read) {
    const int tid = threadIdx.x;
    const int wv = tid >> 6, lane = tid & 63;   // wv 0..7
    const int m0 = blockIdx.x * 16;

    __shared__ float sS[4][16];
    __shared__ float sL[4][16];
    __shared__ uint  sD[4];
    __shared__ float sred[4][16][64];   // dirty-path read partials, 16 KB

    const float4 z4 = make_float4(0.0f, 0.0f, 0.0f, 0.0f);

    if (wv >= 4) {
        // ================= storer waves (4..7) =================
        const int sw = wv - 4;
        float4* base = (float4*)(out_w + (long)m0 * NM);   // 16384 float4
#pragma unroll 8
        for (int it = 0; it < 64; it++)
            base[it * 256 + sw * 64 + lane] = z4;          // 1 KB/instr streams
        if (sw == 0) {
            float4* rb = (float4*)(out_read + (long)m0 * HD);  // 256 float4
#pragma unroll
            for (int it = 0; it < 4; it++) rb[it * 64 + lane] = z4;
        }
        __syncthreads();   // B1: implicit vmcnt(0) drains this wave's zeros
        __syncthreads();   // B2
        const uint anyd = sD[0] | sD[1] | sD[2] | sD[3];
        if (anyd) {        // rare: match computers' extra barriers
            __syncthreads();   // B3
            __syncthreads();   // B4
        }
        return;
    }

    // ================= compute waves (0..3) =================
    const int q = lane >> 4, c = lane & 15;
    const int nbase = wv * 1024;
    const bf16x8 a0 = *(const bf16x8*)(xb + (long)(m0 + c) * HD + q * 8);
    const bf16x8 a1 = *(const bf16x8*)(xb + (long)(m0 + c) * HD + q * 8 + 32);
    const ushort* mstrip = mbs + (long)(wv * 64) * 1024;   // wave's 64 chunks

    // ---- P1: sum-exp + coarse gate bank (loads only; no stores) ----
    float tmax8[8];
    float sm[4] = {0.0f, 0.0f, 0.0f, 0.0f};
    for (int g = 0; g < 8; g++) {
        float tm = -1e30f;
#pragma unroll 4
        for (int ii = 0; ii < 8; ii++) {
            const int i = g * 8 + ii;
            const ushort* mc = mstrip + (long)i * 1024 + lane * 8;
            const bf16x8 b0 = *(const bf16x8*)(mc);
            const bf16x8 b1 = *(const bf16x8*)(mc + 512);
            f32x4 t = {0.0f, 0.0f, 0.0f, 0.0f};
            t = __builtin_amdgcn_mfma_f32_16x16x32_bf16(a0, b0, t, 0, 0, 0);
            t = __builtin_amdgcn_mfma_f32_16x16x32_bf16(a1, b1, t, 0, 0, 0);
            tm = fmaxf(tm, fmaxf(fmaxf(t[0], t[1]), fmaxf(t[2], t[3])));
#pragma unroll
            for (int r = 0; r < 4; r++) sm[r] += __expf(t[r]);
        }
        tmax8[g] = tm;
    }
#pragma unroll
    for (int o = 1; o < 16; o <<= 1)
#pragma unroll
        for (int r = 0; r < 4; r++) sm[r] += __shfl_xor(sm[r], o, 64);
    if (c == 0)
#pragma unroll
        for (int r = 0; r < 4; r++) sS[wv][q * 4 + r] = sm[r];
    __syncthreads();   // B1 (joins storer drain)
    float rS[4], tmin = 1e30f;
#pragma unroll
    for (int r = 0; r < 4; r++) {
        const float S = sS[0][q * 4 + r] + sS[1][q * 4 + r] +
                        sS[2][q * 4 + r] + sS[3][q * 4 + r];
        rS[r] = 1.0f / S;
        const float tau = __logf(0.0025f * S) - 1e-3f;  // conservative
        tmin = fminf(tmin, tau);
    }
    uint dmask = 0;
#pragma unroll
    for (int g = 0; g < 8; g++)
        if (__ballot(tmax8[g] > tmin)) dmask |= 1u << g;
    if (lane == 0) sD[wv] = dmask;
    __syncthreads();   // B2
    const uint anyd = sD[0] | sD[1] | sD[2] | sD[3];

    if (!anyd) return;  // clean (common): storers already wrote everything

    // ================= dirty block (rare): exact path =================
    // gated L1 over 8-chunk groups
    float l1[4] = {0.0f, 0.0f, 0.0f, 0.0f};
    for (int g = 0; g < 8; g++) {
        if (!((dmask >> g) & 1u)) continue;   // wave-uniform
        for (int ii = 0; ii < 8; ii++) {
            const int i = g * 8 + ii;
            const ushort* mc = mstrip + (long)i * 1024 + lane * 8;
            const bf16x8 b0 = *(const bf16x8*)(mc);
            const bf16x8 b1 = *(const bf16x8*)(mc + 512);
            f32x4 t = {0.0f, 0.0f, 0.0f, 0.0f};
            t = __builtin_amdgcn_mfma_f32_16x16x32_bf16(a0, b0, t, 0, 0, 0);
            t = __builtin_amdgcn_mfma_f32_16x16x32_bf16(a1, b1, t, 0, 0, 0);
#pragma unroll
            for (int r = 0; r < 4; r++) {
                float w = __expf(t[r]) * rS[r];
                float d = w - 0.0025f;
                l1[r] += __fdividef(fmaxf(d, 0.0f) * w, fabsf(d) + 1e-12f);
            }
        }
    }
#pragma unroll
    for (int o = 1; o < 16; o <<= 1)
#pragma unroll
        for (int r = 0; r < 4; r++) l1[r] += __shfl_xor(l1[r], o, 64);
    if (c == 0)
#pragma unroll
        for (int r = 0; r < 4; r++) sL[wv][q * 4 + r] = l1[r];
    __syncthreads();   // B3
    float rL[4];
#pragma unroll
    for (int r = 0; r < 4; r++)
        rL[r] = 1.0f / fmaxf(sL[0][q * 4 + r] + sL[1][q * 4 + r] +
                             sL[2][q * 4 + r] + sL[3][q * 4 + r], 1e-12f);

    // full exact recompute + store (overwrites drained zeros) + read accum
    float racc[16];
#pragma unroll
    for (int r = 0; r < 16; r++) racc[r] = 0.0f;
    float* wbase = out_w + (long)(m0 + q * 4) * NM + c;
    for (int i = 0; i < 64; i++) {
        const int n0 = nbase + i * 16;
        const ushort* mc = mstrip + (long)i * 1024 + lane * 8;
        const bf16x8 b0 = *(const bf16x8*)(mc);
        const bf16x8 b1 = *(const bf16x8*)(mc + 512);
        f32x4 t = {0.0f, 0.0f, 0.0f, 0.0f};
        t = __builtin_amdgcn_mfma_f32_16x16x32_bf16(a0, b0, t, 0, 0, 0);
        t = __builtin_amdgcn_mfma_f32_16x16x32_bf16(a1, b1, t, 0, 0, 0);
        float wf[4];
#pragma unroll
        for (int r = 0; r < 4; r++) {
            float w  = __expf(t[r]) * rS[r];
            float d  = w - 0.0025f;
            float sh = __fdividef(fmaxf(d, 0.0f) * w, fabsf(d) + 1e-12f);
            wf[r] = sh * rL[r];
            wbase[(long)r * NM + n0] = wf[r];
        }
        const bool nz = (wf[0] != 0.0f) | (wf[1] != 0.0f) |
                        (wf[2] != 0.0f) | (wf[3] != 0.0f);
        unsigned long long mask = __ballot(nz);
        while (mask) {
            const int j = __ffsll((long long)mask) - 1;
            mask &= (mask - 1);
            const int qj = j >> 4, cj = j & 15;
            float b0v = __shfl(wf[0], j, 64), b1v = __shfl(wf[1], j, 64);
            float b2v = __shfl(wf[2], j, 64), b3v = __shfl(wf[3], j, 64);
            const float mv = mem[(long)(n0 + cj) * HD + lane];
            switch (qj) {  // wave-uniform branch
                case 0: racc[0]  += b0v * mv; racc[1]  += b1v * mv;
                        racc[2]  += b2v * mv; racc[3]  += b3v * mv; break;
                case 1: racc[4]  += b0v * mv; racc[5]  += b1v * mv;
                        racc[6]  += b2v * mv; racc[7]  += b3v * mv; break;
                case 2: racc[8]  += b0v * mv; racc[9]  += b1v * mv;
                        racc[10] += b2v * mv; racc[11] += b3v * mv; break;
                default: racc[12] += b0v * mv; racc[13] += b1v * mv;
                         racc[14] += b2v * mv; racc[15] += b3v * mv; break;
            }
        }
    }

    // combine read partials across compute waves, overwrite out_read
#pragma unroll
    for (int r = 0; r < 16; r++) sred[wv][r][lane] = racc[r];
    __syncthreads();   // B4
#pragma unroll
    for (int rr = 0; rr < 4; rr++) {
        const int row = wv * 4 + rr;
        const float v = sred[0][row][lane] + sred[1][row][lane] +
                        sred[2][row][lane] + sred[3][row][lane];
        out_read[(long)(m0 + row) * HD + lane] = v;
    }
}

extern "C" void kernel_launch(void* const* d_in, const int* in_sizes, int n_in,
                              void* d_out, int out_size, void* d_ws, size_t ws_size,
                              hipStream_t stream) {
    const float* x   = (const float*)d_in[0];
    const float* mem = (const float*)d_in[1];
    ushort* xb       = (ushort*)d_ws;                 // 4 MB
    ushort* mbs      = xb + (long)NROWS * HD;         // 512 KB (swizzled B)
    float* out_read  = (float*)d_out;                 // [32768*64]
    float* out_w     = out_read + (long)NROWS * HD;   // [32768*4096]

    prep_rows<<<NROWS / 4, 256, 0, stream>>>(x, xb, 2.0f);  // 1/T folded
    prep_m_swz<<<NM / 4, 256, 0, stream>>>(mem, mbs);
    k_ps<<<NROWS / 16, 512, 0, stream>>>(xb, mbs, mem, out_w, out_read);
}